// Round 1
// baseline (1306.679 us; speedup 1.0000x reference)
//
#include <hip/hip_runtime.h>

#define D_DIM 1024
#define NF 513            // rfft bins = D/2+1
#define NB 4              // batch
#define NS 2048           // sequence
#define NTOK (NB * NS)    // 8192 tokens
#define NCH 32            // cumsum chunks
#define CHS (NS / NCH)    // 64 steps per chunk

// ---------------------------------------------------------------------------
// GEMM: C[M,N] = A[M,K] * W[N,K]^T   (both row-major, K contiguous: NT gemm)
// 64x64 tile, BK=16, 256 threads, 4x4 microtile per thread.
// ---------------------------------------------------------------------------
__global__ __launch_bounds__(256) void gemm_nt(const float* __restrict__ A,
                                               const float* __restrict__ W,
                                               float* __restrict__ C,
                                               int M, int N, int K) {
    __shared__ float As[16][68];   // [k][m], stride 68 keeps float4 16B-aligned
    __shared__ float Bs[16][68];   // [k][n]
    const int tid = threadIdx.x;
    const int bm = blockIdx.x * 64;
    const int bn = blockIdx.y * 64;
    const int tx = tid & 15, ty = tid >> 4;
    const int lr = tid >> 2;              // 0..63 row within tile
    const int lc = (tid & 3) << 2;        // 0,4,8,12 k offset
    float acc[4][4] = {{0.f}};
    const float* Arow = A + (size_t)(bm + lr) * K + lc;
    const float* Wrow = W + (size_t)(bn + lr) * K + lc;
    for (int k0 = 0; k0 < K; k0 += 16) {
        float4 a4 = *reinterpret_cast<const float4*>(Arow + k0);
        float4 b4 = *reinterpret_cast<const float4*>(Wrow + k0);
        __syncthreads();
        As[lc + 0][lr] = a4.x; As[lc + 1][lr] = a4.y; As[lc + 2][lr] = a4.z; As[lc + 3][lr] = a4.w;
        Bs[lc + 0][lr] = b4.x; Bs[lc + 1][lr] = b4.y; Bs[lc + 2][lr] = b4.z; Bs[lc + 3][lr] = b4.w;
        __syncthreads();
#pragma unroll
        for (int kk = 0; kk < 16; ++kk) {
            float4 av = *reinterpret_cast<const float4*>(&As[kk][ty * 4]);
            float4 bv = *reinterpret_cast<const float4*>(&Bs[kk][tx * 4]);
            acc[0][0] += av.x * bv.x; acc[0][1] += av.x * bv.y; acc[0][2] += av.x * bv.z; acc[0][3] += av.x * bv.w;
            acc[1][0] += av.y * bv.x; acc[1][1] += av.y * bv.y; acc[1][2] += av.y * bv.z; acc[1][3] += av.y * bv.w;
            acc[2][0] += av.z * bv.x; acc[2][1] += av.z * bv.y; acc[2][2] += av.z * bv.z; acc[2][3] += av.z * bv.w;
            acc[3][0] += av.w * bv.x; acc[3][1] += av.w * bv.y; acc[3][2] += av.w * bv.z; acc[3][3] += av.w * bv.w;
        }
    }
#pragma unroll
    for (int i = 0; i < 4; ++i) {
        float4 o = make_float4(acc[i][0], acc[i][1], acc[i][2], acc[i][3]);
        *reinterpret_cast<float4*>(&C[(size_t)(bm + ty * 4 + i) * N + bn + tx * 4]) = o;
    }
}

// ---------------------------------------------------------------------------
// 1024-point complex FFT in LDS, iterative DIT radix-2, input pre-bit-reversed.
// 256 threads, each does 2 butterflies per stage. Ends with __syncthreads().
// ---------------------------------------------------------------------------
__device__ inline void fft1024_lds(float* re, float* im,
                                   const float* twr, const float* twi) {
#pragma unroll
    for (int s = 0; s < 10; ++s) {
        const int half = 1 << s;
        const int step = 512 >> s;   // N / len
#pragma unroll
        for (int jj = 0; jj < 2; ++jj) {
            int j = threadIdx.x + (jj << 8);
            int pos = j & (half - 1);
            int i0 = ((j >> s) << (s + 1)) + pos;
            int i1 = i0 + half;
            float wr = twr[pos * step], wi = twi[pos * step];
            float xr = re[i1], xi = im[i1];
            float tr = wr * xr - wi * xi;
            float ti = wr * xi + wi * xr;
            float ur = re[i0], ui = im[i0];
            re[i1] = ur - tr; im[i1] = ui - ti;
            re[i0] = ur + tr; im[i0] = ui + ti;
        }
        __syncthreads();
    }
}

__device__ inline void load_bitrev_real(float* re, float* im, const float* src) {
    for (int n = threadIdx.x; n < 1024; n += 256) {
        int r = __brev((unsigned)n) >> 22;
        re[r] = src[n];
        im[r] = 0.f;
    }
}

// ---------------------------------------------------------------------------
// Per-token forward FFTs: Fkv = rfft(k)*rfft(v), Fq = rfft(q)
// ---------------------------------------------------------------------------
__global__ __launch_bounds__(256) void hrr_fft_fwd(const float* __restrict__ Q,
                                                   const float* __restrict__ Kp,
                                                   const float* __restrict__ V,
                                                   float2* __restrict__ Fkv,
                                                   float2* __restrict__ Fq) {
    __shared__ float twr[512], twi[512];
    __shared__ float re[1024], im[1024];
    __shared__ float svr[NF], svi[NF];
    const int tid = threadIdx.x;
    const int tok = blockIdx.x;
    for (int j = tid; j < 512; j += 256) {
        float ang = -6.283185307179586f * (float)j / 1024.0f;
        float sv, cv;
        sincosf(ang, &sv, &cv);
        twr[j] = cv; twi[j] = sv;
    }
    // V
    load_bitrev_real(re, im, V + (size_t)tok * D_DIM);
    __syncthreads();
    fft1024_lds(re, im, twr, twi);
    for (int j = tid; j < NF; j += 256) { svr[j] = re[j]; svi[j] = im[j]; }
    __syncthreads();
    // K
    load_bitrev_real(re, im, Kp + (size_t)tok * D_DIM);
    __syncthreads();
    fft1024_lds(re, im, twr, twi);
    for (int j = tid; j < NF; j += 256) {
        float kr = re[j], ki = im[j];
        float vr = svr[j], vi = svi[j];
        Fkv[(size_t)tok * NF + j] = make_float2(kr * vr - ki * vi, kr * vi + ki * vr);
    }
    __syncthreads();
    // Q
    load_bitrev_real(re, im, Q + (size_t)tok * D_DIM);
    __syncthreads();
    fft1024_lds(re, im, twr, twi);
    for (int j = tid; j < NF; j += 256) {
        Fq[(size_t)tok * NF + j] = make_float2(re[j], im[j]);
    }
}

// ---------------------------------------------------------------------------
// Chunked causal cumsum over s per (b, f), then U = Fmem * conj(Fq) in place.
// ---------------------------------------------------------------------------
__global__ __launch_bounds__(256) void hrr_chunk_sum(const float2* __restrict__ Fkv,
                                                     float2* __restrict__ part) {
    int f = blockIdx.x * 256 + threadIdx.x;
    if (f >= NF) return;
    int ch = blockIdx.y, b = blockIdx.z;
    float sx = 0.f, sy = 0.f;
    size_t base = ((size_t)b * NS + (size_t)ch * CHS) * NF + f;
    for (int i = 0; i < CHS; ++i) {
        float2 t = Fkv[base + (size_t)i * NF];
        sx += t.x; sy += t.y;
    }
    part[(size_t)(b * NCH + ch) * NF + f] = make_float2(sx, sy);
}

__global__ __launch_bounds__(256) void hrr_chunk_scan(float2* __restrict__ part) {
    int g = blockIdx.x * 256 + threadIdx.x;
    if (g >= NB * NF) return;
    int b = g / NF, f = g % NF;
    float rx = 0.f, ry = 0.f;
    for (int ch = 0; ch < NCH; ++ch) {
        size_t idx = (size_t)(b * NCH + ch) * NF + f;
        float2 t = part[idx];
        part[idx] = make_float2(rx, ry);   // exclusive prefix of chunk totals
        rx += t.x; ry += t.y;
    }
}

__global__ __launch_bounds__(256) void hrr_scan_apply(float2* __restrict__ Fkv,
                                                      const float2* __restrict__ Fq,
                                                      const float2* __restrict__ part) {
    int f = blockIdx.x * 256 + threadIdx.x;
    if (f >= NF) return;
    int ch = blockIdx.y, b = blockIdx.z;
    float2 run = part[(size_t)(b * NCH + ch) * NF + f];
    size_t base = ((size_t)b * NS + (size_t)ch * CHS) * NF + f;
    for (int i = 0; i < CHS; ++i) {
        size_t idx = base + (size_t)i * NF;
        float2 kv = Fkv[idx];
        run.x += kv.x; run.y += kv.y;
        float2 q = Fq[idx];
        // U = mem * conj(q) : (a+bi)(c-di) = (ac+bd) + i(bc-ad)
        Fkv[idx] = make_float2(run.x * q.x + run.y * q.y,
                               run.y * q.x - run.x * q.y);
    }
}

// ---------------------------------------------------------------------------
// Per-token irfft of U (Hermitian) via forward FFT of conj(U_full).
// ---------------------------------------------------------------------------
__global__ __launch_bounds__(256) void hrr_ifft(const float2* __restrict__ U,
                                                float* __restrict__ vhat) {
    __shared__ float twr[512], twi[512];
    __shared__ float re[1024], im[1024];
    const int tid = threadIdx.x;
    const int tok = blockIdx.x;
    for (int j = tid; j < 512; j += 256) {
        float ang = -6.283185307179586f * (float)j / 1024.0f;
        float sv, cv;
        sincosf(ang, &sv, &cv);
        twr[j] = cv; twi[j] = sv;
    }
    const float2* up = U + (size_t)tok * NF;
    for (int n = tid; n < 1024; n += 256) {
        float cr, ci;
        if (n <= 512) { float2 c = up[n];        cr = c.x; ci = -c.y; }
        else          { float2 c = up[1024 - n]; cr = c.x; ci =  c.y; }
        int r = __brev((unsigned)n) >> 22;
        re[r] = cr; im[r] = ci;
    }
    __syncthreads();
    fft1024_lds(re, im, twr, twi);
    const float invN = 1.0f / 1024.0f;
    for (int n = tid; n < 1024; n += 256)
        vhat[(size_t)tok * D_DIM + n] = re[n] * invN;
}

// ---------------------------------------------------------------------------
extern "C" void kernel_launch(void* const* d_in, const int* in_sizes, int n_in,
                              void* d_out, int out_size, void* d_ws, size_t ws_size,
                              hipStream_t stream) {
    const float* x  = (const float*)d_in[0];
    const float* Wq = (const float*)d_in[1];
    const float* Wk = (const float*)d_in[2];
    const float* Wv = (const float*)d_in[3];
    const float* Wo = (const float*)d_in[4];
    float* out = (float*)d_out;

    char* ws = (char*)d_ws;
    // sizes: Q/K/V = 8192*1024*4 = 33,554,432 ; Fkv/Fq = 8192*513*8 = 33,619,968
    float*  Q    = (float*) (ws + 0);
    float*  Kb   = (float*) (ws + 33554432);
    float*  Vb   = (float*) (ws + 67108864);
    float2* Fkv  = (float2*)(ws + 100663296);
    float2* Fq   = (float2*)(ws + 134283264);
    float2* part = (float2*)(ws + 167903232);  // 4*32*513*8 = 525,312 bytes
    float*  vhat = Q;  // Q dead after hrr_fft_fwd

    dim3 gg(NTOK / 64, D_DIM / 64);
    gemm_nt<<<gg, 256, 0, stream>>>(x, Wq, Q,  NTOK, D_DIM, D_DIM);
    gemm_nt<<<gg, 256, 0, stream>>>(x, Wk, Kb, NTOK, D_DIM, D_DIM);
    gemm_nt<<<gg, 256, 0, stream>>>(x, Wv, Vb, NTOK, D_DIM, D_DIM);

    hrr_fft_fwd<<<NTOK, 256, 0, stream>>>(Q, Kb, Vb, Fkv, Fq);

    dim3 gs((NF + 255) / 256, NCH, NB);
    hrr_chunk_sum<<<gs, 256, 0, stream>>>(Fkv, part);
    hrr_chunk_scan<<<(NB * NF + 255) / 256, 256, 0, stream>>>(part);
    hrr_scan_apply<<<gs, 256, 0, stream>>>(Fkv, Fq, part);

    hrr_ifft<<<NTOK, 256, 0, stream>>>(Fkv, vhat);

    gemm_nt<<<gg, 256, 0, stream>>>(vhat, Wo, out, NTOK, D_DIM, D_DIM);
}

// Round 2
// 458.990 us; speedup vs baseline: 2.8469x; 2.8469x over previous
//
#include <hip/hip_runtime.h>

#define D_DIM 1024
#define NF 513            // rfft bins = D/2+1
#define NB 4              // batch
#define NS 2048           // sequence
#define NTOK (NB * NS)    // 8192 tokens
#define NCH 32            // cumsum chunks
#define CHS (NS / NCH)    // 64 steps per chunk

typedef __attribute__((ext_vector_type(8))) short short8_t;   // 8 bf16 = 4 VGPRs
typedef __attribute__((ext_vector_type(4))) float f32x4;

__device__ inline unsigned short f2bf(float f) {
    unsigned u = __builtin_bit_cast(unsigned, f);
    u += 0x7FFFu + ((u >> 16) & 1u);   // round-to-nearest-even
    return (unsigned short)(u >> 16);
}

__global__ __launch_bounds__(256) void convert_f32_bf16(const float* __restrict__ src,
                                                        unsigned short* __restrict__ dst,
                                                        int n4) {
    int i = blockIdx.x * 256 + threadIdx.x;
    int stride = gridDim.x * 256;
    for (; i < n4; i += stride) {
        float4 v = reinterpret_cast<const float4*>(src)[i];
        ushort4 o;
        o.x = f2bf(v.x); o.y = f2bf(v.y); o.z = f2bf(v.z); o.w = f2bf(v.w);
        reinterpret_cast<ushort4*>(dst)[i] = o;
    }
}

// ---------------------------------------------------------------------------
// bf16 MFMA GEMM: C[M,N] = A[M,K] * B[N,K]^T, fp32 out.  128x128 tile, BK=32,
// 4 waves (2x2), each wave 64x64 = 4x4 fragments of 16x16x32 MFMA.
// global_load_lds width-16 staging, linear LDS layout [row][k].
// ---------------------------------------------------------------------------
#define BM 128
#define BN 128
#define BK 32

__device__ inline void gload_lds16(const void* g, void* l) {
    __builtin_amdgcn_global_load_lds(
        (const __attribute__((address_space(1))) void*)g,
        (__attribute__((address_space(3))) void*)l,
        16, 0, 0);
}

__global__ __launch_bounds__(256) void gemm_bf16_nt(const unsigned short* __restrict__ A,
                                                    const unsigned short* __restrict__ B,
                                                    float* __restrict__ C,
                                                    int M, int N, int K) {
    __shared__ __attribute__((aligned(16))) unsigned short ldsA[BM * BK];
    __shared__ __attribute__((aligned(16))) unsigned short ldsB[BN * BK];
    const int tid  = threadIdx.x;
    const int wave = tid >> 6;
    const int lane = tid & 63;
    const int l15  = lane & 15;
    const int k8   = (lane >> 4) << 3;       // 0,8,16,24
    const int wm   = (wave >> 1) * 64;
    const int wn   = (wave & 1) * 64;
    const int bm   = blockIdx.x * BM;
    const int bn   = blockIdx.y * BN;
    const int crow = tid >> 2;               // staging row (c=0): 0..63
    const int ccol = (tid & 3) << 3;         // staging k-offset: 0,8,16,24

    f32x4 acc[4][4];
#pragma unroll
    for (int i = 0; i < 4; ++i)
#pragma unroll
        for (int j = 0; j < 4; ++j)
            acc[i][j] = (f32x4){0.f, 0.f, 0.f, 0.f};

    for (int k0 = 0; k0 < K; k0 += BK) {
        __syncthreads();   // prev iteration's LDS reads complete
#pragma unroll
        for (int c = 0; c < 2; ++c) {
            int row = crow + (c << 6);
            gload_lds16(A + (size_t)(bm + row) * K + k0 + ccol, &ldsA[row * BK + ccol]);
            gload_lds16(B + (size_t)(bn + row) * K + k0 + ccol, &ldsB[row * BK + ccol]);
        }
        __syncthreads();   // drains vmcnt: staged data visible

        short8_t af[4], bf[4];
#pragma unroll
        for (int mi = 0; mi < 4; ++mi)
            af[mi] = *reinterpret_cast<const short8_t*>(&ldsA[(wm + mi * 16 + l15) * BK + k8]);
#pragma unroll
        for (int ni = 0; ni < 4; ++ni)
            bf[ni] = *reinterpret_cast<const short8_t*>(&ldsB[(wn + ni * 16 + l15) * BK + k8]);
#pragma unroll
        for (int mi = 0; mi < 4; ++mi)
#pragma unroll
            for (int ni = 0; ni < 4; ++ni)
                acc[mi][ni] = __builtin_amdgcn_mfma_f32_16x16x32_bf16(af[mi], bf[ni], acc[mi][ni], 0, 0, 0);
    }

    // C/D layout: col = lane&15, row = (lane>>4)*4 + j   [m89-verified]
#pragma unroll
    for (int mi = 0; mi < 4; ++mi) {
        int rbase = bm + wm + mi * 16 + (lane >> 4) * 4;
#pragma unroll
        for (int ni = 0; ni < 4; ++ni) {
            int col = bn + wn + ni * 16 + l15;
#pragma unroll
            for (int j = 0; j < 4; ++j)
                C[(size_t)(rbase + j) * N + col] = acc[mi][ni][j];
        }
    }
}

// ---------------------------------------------------------------------------
// 1024-point complex FFT in LDS, iterative DIT radix-2, input pre-bit-reversed.
// ---------------------------------------------------------------------------
__device__ inline void fft1024_lds(float* re, float* im,
                                   const float* twr, const float* twi) {
#pragma unroll
    for (int s = 0; s < 10; ++s) {
        const int half = 1 << s;
        const int step = 512 >> s;
#pragma unroll
        for (int jj = 0; jj < 2; ++jj) {
            int j = threadIdx.x + (jj << 8);
            int pos = j & (half - 1);
            int i0 = ((j >> s) << (s + 1)) + pos;
            int i1 = i0 + half;
            float wr = twr[pos * step], wi = twi[pos * step];
            float xr = re[i1], xi = im[i1];
            float tr = wr * xr - wi * xi;
            float ti = wr * xi + wi * xr;
            float ur = re[i0], ui = im[i0];
            re[i1] = ur - tr; im[i1] = ui - ti;
            re[i0] = ur + tr; im[i0] = ui + ti;
        }
        __syncthreads();
    }
}

__device__ inline void load_bitrev_real(float* re, float* im, const float* src) {
    for (int n = threadIdx.x; n < 1024; n += 256) {
        int r = __brev((unsigned)n) >> 22;
        re[r] = src[n];
        im[r] = 0.f;
    }
}

__global__ __launch_bounds__(256) void hrr_fft_fwd(const float* __restrict__ Q,
                                                   const float* __restrict__ Kp,
                                                   const float* __restrict__ V,
                                                   float2* __restrict__ Fkv,
                                                   float2* __restrict__ Fq) {
    __shared__ float twr[512], twi[512];
    __shared__ float re[1024], im[1024];
    __shared__ float svr[NF], svi[NF];
    const int tid = threadIdx.x;
    const int tok = blockIdx.x;
    for (int j = tid; j < 512; j += 256) {
        float ang = -6.283185307179586f * (float)j / 1024.0f;
        float sv, cv;
        sincosf(ang, &sv, &cv);
        twr[j] = cv; twi[j] = sv;
    }
    load_bitrev_real(re, im, V + (size_t)tok * D_DIM);
    __syncthreads();
    fft1024_lds(re, im, twr, twi);
    for (int j = tid; j < NF; j += 256) { svr[j] = re[j]; svi[j] = im[j]; }
    __syncthreads();
    load_bitrev_real(re, im, Kp + (size_t)tok * D_DIM);
    __syncthreads();
    fft1024_lds(re, im, twr, twi);
    for (int j = tid; j < NF; j += 256) {
        float kr = re[j], ki = im[j];
        float vr = svr[j], vi = svi[j];
        Fkv[(size_t)tok * NF + j] = make_float2(kr * vr - ki * vi, kr * vi + ki * vr);
    }
    __syncthreads();
    load_bitrev_real(re, im, Q + (size_t)tok * D_DIM);
    __syncthreads();
    fft1024_lds(re, im, twr, twi);
    for (int j = tid; j < NF; j += 256) {
        Fq[(size_t)tok * NF + j] = make_float2(re[j], im[j]);
    }
}

// ---------------------------------------------------------------------------
// Chunked causal cumsum over s per (b, f), then U = Fmem * conj(Fq) in place.
// ---------------------------------------------------------------------------
__global__ __launch_bounds__(256) void hrr_chunk_sum(const float2* __restrict__ Fkv,
                                                     float2* __restrict__ part) {
    int f = blockIdx.x * 256 + threadIdx.x;
    if (f >= NF) return;
    int ch = blockIdx.y, b = blockIdx.z;
    float sx = 0.f, sy = 0.f;
    size_t base = ((size_t)b * NS + (size_t)ch * CHS) * NF + f;
    for (int i = 0; i < CHS; ++i) {
        float2 t = Fkv[base + (size_t)i * NF];
        sx += t.x; sy += t.y;
    }
    part[(size_t)(b * NCH + ch) * NF + f] = make_float2(sx, sy);
}

__global__ __launch_bounds__(256) void hrr_chunk_scan(float2* __restrict__ part) {
    int g = blockIdx.x * 256 + threadIdx.x;
    if (g >= NB * NF) return;
    int b = g / NF, f = g % NF;
    float rx = 0.f, ry = 0.f;
    for (int ch = 0; ch < NCH; ++ch) {
        size_t idx = (size_t)(b * NCH + ch) * NF + f;
        float2 t = part[idx];
        part[idx] = make_float2(rx, ry);
        rx += t.x; ry += t.y;
    }
}

__global__ __launch_bounds__(256) void hrr_scan_apply(float2* __restrict__ Fkv,
                                                      const float2* __restrict__ Fq,
                                                      const float2* __restrict__ part) {
    int f = blockIdx.x * 256 + threadIdx.x;
    if (f >= NF) return;
    int ch = blockIdx.y, b = blockIdx.z;
    float2 run = part[(size_t)(b * NCH + ch) * NF + f];
    size_t base = ((size_t)b * NS + (size_t)ch * CHS) * NF + f;
    for (int i = 0; i < CHS; ++i) {
        size_t idx = base + (size_t)i * NF;
        float2 kv = Fkv[idx];
        run.x += kv.x; run.y += kv.y;
        float2 q = Fq[idx];
        Fkv[idx] = make_float2(run.x * q.x + run.y * q.y,
                               run.y * q.x - run.x * q.y);
    }
}

// ---------------------------------------------------------------------------
// Per-token irfft of U (Hermitian), writes vhat as bf16 for the final GEMM.
// ---------------------------------------------------------------------------
__global__ __launch_bounds__(256) void hrr_ifft(const float2* __restrict__ U,
                                                unsigned short* __restrict__ vhat) {
    __shared__ float twr[512], twi[512];
    __shared__ float re[1024], im[1024];
    const int tid = threadIdx.x;
    const int tok = blockIdx.x;
    for (int j = tid; j < 512; j += 256) {
        float ang = -6.283185307179586f * (float)j / 1024.0f;
        float sv, cv;
        sincosf(ang, &sv, &cv);
        twr[j] = cv; twi[j] = sv;
    }
    const float2* up = U + (size_t)tok * NF;
    for (int n = tid; n < 1024; n += 256) {
        float cr, ci;
        if (n <= 512) { float2 c = up[n];        cr = c.x; ci = -c.y; }
        else          { float2 c = up[1024 - n]; cr = c.x; ci =  c.y; }
        int r = __brev((unsigned)n) >> 22;
        re[r] = cr; im[r] = ci;
    }
    __syncthreads();
    fft1024_lds(re, im, twr, twi);
    const float invN = 1.0f / 1024.0f;
    for (int n = tid; n < 1024; n += 256)
        vhat[(size_t)tok * D_DIM + n] = f2bf(re[n] * invN);
}

// ---------------------------------------------------------------------------
extern "C" void kernel_launch(void* const* d_in, const int* in_sizes, int n_in,
                              void* d_out, int out_size, void* d_ws, size_t ws_size,
                              hipStream_t stream) {
    const float* x  = (const float*)d_in[0];
    const float* Wq = (const float*)d_in[1];
    const float* Wk = (const float*)d_in[2];
    const float* Wv = (const float*)d_in[3];
    const float* Wo = (const float*)d_in[4];
    float* out = (float*)d_out;

    char* ws = (char*)d_ws;
    // fp32 projections
    float*  Q    = (float*) (ws + 0);          // 33,554,432 B (reused as vhat bf16)
    float*  Kb   = (float*) (ws + 33554432);
    float*  Vb   = (float*) (ws + 67108864);
    float2* Fkv  = (float2*)(ws + 100663296);  // 33,619,968 B
    float2* Fq   = (float2*)(ws + 134283264);  // 33,619,968 B
    float2* part = (float2*)(ws + 167903232);  // 525,312 B
    unsigned short* Wob = (unsigned short*)(ws + 168428544);  // 2,097,152 B  (end ~170.5 MB)
    // aliases (dead-before-written):
    unsigned short* xb   = (unsigned short*)Fkv;  // x bf16, 16.78 MB; dead before Fkv written
    unsigned short* Wqb  = (unsigned short*)Fq;   // W bf16 x3 in Fq region; dead before Fq written
    unsigned short* Wkb  = Wqb + 1024 * 1024;
    unsigned short* Wvb  = Wkb + 1024 * 1024;
    unsigned short* vhat = (unsigned short*)Q;    // Q fp32 dead after hrr_fft_fwd

    convert_f32_bf16<<<2048, 256, 0, stream>>>(x,  xb,  NTOK * D_DIM / 4);
    convert_f32_bf16<<<1024, 256, 0, stream>>>(Wq, Wqb, D_DIM * D_DIM / 4);
    convert_f32_bf16<<<1024, 256, 0, stream>>>(Wk, Wkb, D_DIM * D_DIM / 4);
    convert_f32_bf16<<<1024, 256, 0, stream>>>(Wv, Wvb, D_DIM * D_DIM / 4);
    convert_f32_bf16<<<1024, 256, 0, stream>>>(Wo, Wob, D_DIM * D_DIM / 4);

    dim3 gg(NTOK / BM, D_DIM / BN);
    gemm_bf16_nt<<<gg, 256, 0, stream>>>(xb, Wqb, Q,  NTOK, D_DIM, D_DIM);
    gemm_bf16_nt<<<gg, 256, 0, stream>>>(xb, Wkb, Kb, NTOK, D_DIM, D_DIM);
    gemm_bf16_nt<<<gg, 256, 0, stream>>>(xb, Wvb, Vb, NTOK, D_DIM, D_DIM);

    hrr_fft_fwd<<<NTOK, 256, 0, stream>>>(Q, Kb, Vb, Fkv, Fq);

    dim3 gs((NF + 255) / 256, NCH, NB);
    hrr_chunk_sum<<<gs, 256, 0, stream>>>(Fkv, part);
    hrr_chunk_scan<<<(NB * NF + 255) / 256, 256, 0, stream>>>(part);
    hrr_scan_apply<<<gs, 256, 0, stream>>>(Fkv, Fq, part);

    hrr_ifft<<<NTOK, 256, 0, stream>>>(Fkv, vhat);

    gemm_bf16_nt<<<gg, 256, 0, stream>>>(vhat, Wob, out, NTOK, D_DIM, D_DIM);
}

// Round 3
// 206.514 us; speedup vs baseline: 6.3273x; 2.2226x over previous
//
#include <hip/hip_runtime.h>

#define D_DIM 1024
#define NF 513            // rfft bins = D/2+1
#define NB 4              // batch
#define NS 2048           // sequence
#define NTOK (NB * NS)    // 8192 tokens
#define NCH 32            // cumsum chunks
#define CHS (NS / NCH)    // 64 steps per chunk

typedef __attribute__((ext_vector_type(8))) short short8_t;   // 8 bf16 = 4 VGPRs
typedef __attribute__((ext_vector_type(4))) float f32x4;

__device__ inline unsigned short f2bf(float f) {
    unsigned u = __builtin_bit_cast(unsigned, f);
    u += 0x7FFFu + ((u >> 16) & 1u);   // round-to-nearest-even
    return (unsigned short)(u >> 16);
}

__global__ __launch_bounds__(256) void convert_f32_bf16(const float* __restrict__ src,
                                                        unsigned short* __restrict__ dst,
                                                        int n4) {
    int i = blockIdx.x * 256 + threadIdx.x;
    int stride = gridDim.x * 256;
    for (; i < n4; i += stride) {
        float4 v = reinterpret_cast<const float4*>(src)[i];
        ushort4 o;
        o.x = f2bf(v.x); o.y = f2bf(v.y); o.z = f2bf(v.z); o.w = f2bf(v.w);
        reinterpret_cast<ushort4*>(dst)[i] = o;
    }
}

// ---------------------------------------------------------------------------
// bf16 MFMA GEMM: C[M,N] = A[M,K] * B[N,K]^T, fp32 out.  128x128 tile, BK=32.
// ---------------------------------------------------------------------------
#define BM 128
#define BN 128
#define BK 32

__device__ inline void gload_lds16(const void* g, void* l) {
    __builtin_amdgcn_global_load_lds(
        (const __attribute__((address_space(1))) void*)g,
        (__attribute__((address_space(3))) void*)l,
        16, 0, 0);
}

__global__ __launch_bounds__(256) void gemm_bf16_nt(const unsigned short* __restrict__ A,
                                                    const unsigned short* __restrict__ B,
                                                    float* __restrict__ C,
                                                    int M, int N, int K) {
    __shared__ __attribute__((aligned(16))) unsigned short ldsA[BM * BK];
    __shared__ __attribute__((aligned(16))) unsigned short ldsB[BN * BK];
    const int tid  = threadIdx.x;
    const int wave = tid >> 6;
    const int lane = tid & 63;
    const int l15  = lane & 15;
    const int k8   = (lane >> 4) << 3;
    const int wm   = (wave >> 1) * 64;
    const int wn   = (wave & 1) * 64;
    const int bm   = blockIdx.x * BM;
    const int bn   = blockIdx.y * BN;
    const int crow = tid >> 2;
    const int ccol = (tid & 3) << 3;

    f32x4 acc[4][4];
#pragma unroll
    for (int i = 0; i < 4; ++i)
#pragma unroll
        for (int j = 0; j < 4; ++j)
            acc[i][j] = (f32x4){0.f, 0.f, 0.f, 0.f};

    for (int k0 = 0; k0 < K; k0 += BK) {
        __syncthreads();
#pragma unroll
        for (int c = 0; c < 2; ++c) {
            int row = crow + (c << 6);
            gload_lds16(A + (size_t)(bm + row) * K + k0 + ccol, &ldsA[row * BK + ccol]);
            gload_lds16(B + (size_t)(bn + row) * K + k0 + ccol, &ldsB[row * BK + ccol]);
        }
        __syncthreads();

        short8_t af[4], bf[4];
#pragma unroll
        for (int mi = 0; mi < 4; ++mi)
            af[mi] = *reinterpret_cast<const short8_t*>(&ldsA[(wm + mi * 16 + l15) * BK + k8]);
#pragma unroll
        for (int ni = 0; ni < 4; ++ni)
            bf[ni] = *reinterpret_cast<const short8_t*>(&ldsB[(wn + ni * 16 + l15) * BK + k8]);
#pragma unroll
        for (int mi = 0; mi < 4; ++mi)
#pragma unroll
            for (int ni = 0; ni < 4; ++ni)
                acc[mi][ni] = __builtin_amdgcn_mfma_f32_16x16x32_bf16(af[mi], bf[ni], acc[mi][ni], 0, 0, 0);
    }

#pragma unroll
    for (int mi = 0; mi < 4; ++mi) {
        int rbase = bm + wm + mi * 16 + (lane >> 4) * 4;
#pragma unroll
        for (int ni = 0; ni < 4; ++ni) {
            int col = bn + wn + ni * 16 + l15;
#pragma unroll
            for (int j = 0; j < 4; ++j)
                C[(size_t)(rbase + j) * N + col] = acc[mi][ni][j];
        }
    }
}

// ---------------------------------------------------------------------------
// Radix-4 1024-pt complex FFT in LDS, float2 elements, XOR bank swizzle.
// sw(i) = i ^ ((i>>4)&15): makes every power-of-2-stride pattern bank-uniform.
// ---------------------------------------------------------------------------
__device__ inline int sw(int i) { return i ^ ((i >> 4) & 15); }

__device__ inline int dr4(int n) {   // reverse 5 base-4 digits of 10-bit n
    return ((n & 3) << 8) | (((n >> 2) & 3) << 6) | (((n >> 4) & 3) << 4) |
           (((n >> 6) & 3) << 2) | ((n >> 8) & 3);
}

__device__ inline float2 cmul(float2 a, float2 b) {
    return make_float2(a.x * b.x - a.y * b.y, a.x * b.y + a.y * b.x);
}

// tw: logical k -> twL[sw(k)] = exp(-2*pi*i*k/1024), k in [0,768)
__device__ inline void fft1024_r4(float2* X, const float2* tw, int t) {
#pragma unroll
    for (int s = 0; s < 5; ++s) {
        const int L = 1 << (2 * s);
        const int r = t & (L - 1);
        const int base = ((t >> (2 * s)) << (2 * s + 2)) + r;
        float2 A  = X[sw(base)];
        float2 Bv = X[sw(base + L)];
        float2 Cv = X[sw(base + 2 * L)];
        float2 Dv = X[sw(base + 3 * L)];
        if (s != 0) {
            const int step = 1024 >> (2 * s + 2);   // 1024/(4L)
            Bv = cmul(Bv, tw[sw(r * step)]);
            Cv = cmul(Cv, tw[sw(2 * r * step)]);
            Dv = cmul(Dv, tw[sw(3 * r * step)]);
        }
        float2 e0 = make_float2(A.x + Cv.x, A.y + Cv.y);
        float2 e1 = make_float2(A.x - Cv.x, A.y - Cv.y);
        float2 o0 = make_float2(Bv.x + Dv.x, Bv.y + Dv.y);
        float2 o1 = make_float2(Bv.x - Dv.x, Bv.y - Dv.y);
        X[sw(base)]         = make_float2(e0.x + o0.x, e0.y + o0.y);
        X[sw(base + L)]     = make_float2(e1.x + o1.y, e1.y - o1.x);   // e1 - i*o1
        X[sw(base + 2 * L)] = make_float2(e0.x - o0.x, e0.y - o0.y);
        X[sw(base + 3 * L)] = make_float2(e1.x - o1.y, e1.y + o1.x);   // e1 + i*o1
        __syncthreads();
    }
}

__global__ __launch_bounds__(256) void twiddle_init(float2* __restrict__ twg) {
    int k = blockIdx.x * 256 + threadIdx.x;
    if (k < 768) {
        float ang = -6.283185307179586f * (float)k / 1024.0f;
        float s, c;
        sincosf(ang, &s, &c);
        twg[sw(k)] = make_float2(c, s);   // stored pre-swizzled
    }
}

// ---------------------------------------------------------------------------
// Forward: block handles tokens (2b, 2b+1). 3 complex FFTs:
//   z = k + i*v (each token)  -> untangle -> Fkv = Fk*Fv
//   z = q(t0) + i*q(t1)       -> untangle -> Fq(t0), Fq(t1)
// QKV layout: [tok][3072] = q|k|v
// ---------------------------------------------------------------------------
__global__ __launch_bounds__(256) void hrr_fft_fwd(const float* __restrict__ QKV,
                                                   const float2* __restrict__ twg,
                                                   float2* __restrict__ Fkv,
                                                   float2* __restrict__ Fq) {
    __shared__ __attribute__((aligned(16))) float2 X[1024];
    __shared__ __attribute__((aligned(16))) float2 twL[768];
    const int tid = threadIdx.x;
    const int t0 = blockIdx.x * 2, t1 = t0 + 1;
    for (int i = tid; i < 384; i += 256)
        reinterpret_cast<float4*>(twL)[i] = reinterpret_cast<const float4*>(twg)[i];

#pragma unroll
    for (int which = 0; which < 2; ++which) {
        const int tok = which ? t1 : t0;
        const float4* Kr = (const float4*)(QKV + (size_t)tok * 3072 + 1024);
        const float4* Vr = (const float4*)(QKV + (size_t)tok * 3072 + 2048);
        float4 k4 = Kr[tid], v4 = Vr[tid];
        X[sw(dr4(4 * tid + 0))] = make_float2(k4.x, v4.x);
        X[sw(dr4(4 * tid + 1))] = make_float2(k4.y, v4.y);
        X[sw(dr4(4 * tid + 2))] = make_float2(k4.z, v4.z);
        X[sw(dr4(4 * tid + 3))] = make_float2(k4.w, v4.w);
        __syncthreads();
        fft1024_r4(X, twL, tid);
        for (int j = tid; j < NF; j += 256) {
            float2 Zj = X[sw(j)];
            float2 Zm = X[sw((1024 - j) & 1023)];
            float2 Fk = make_float2(0.5f * (Zj.x + Zm.x), 0.5f * (Zj.y - Zm.y));
            float2 Fv = make_float2(0.5f * (Zj.y + Zm.y), 0.5f * (Zm.x - Zj.x));
            Fkv[(size_t)tok * NF + j] = cmul(Fk, Fv);
        }
        __syncthreads();
    }
    // Q pair
    {
        const float4* Q0 = (const float4*)(QKV + (size_t)t0 * 3072);
        const float4* Q1 = (const float4*)(QKV + (size_t)t1 * 3072);
        float4 a4 = Q0[tid], b4 = Q1[tid];
        X[sw(dr4(4 * tid + 0))] = make_float2(a4.x, b4.x);
        X[sw(dr4(4 * tid + 1))] = make_float2(a4.y, b4.y);
        X[sw(dr4(4 * tid + 2))] = make_float2(a4.z, b4.z);
        X[sw(dr4(4 * tid + 3))] = make_float2(a4.w, b4.w);
        __syncthreads();
        fft1024_r4(X, twL, tid);
        for (int j = tid; j < NF; j += 256) {
            float2 Zj = X[sw(j)];
            float2 Zm = X[sw((1024 - j) & 1023)];
            float2 f0 = make_float2(0.5f * (Zj.x + Zm.x), 0.5f * (Zj.y - Zm.y));
            float2 f1 = make_float2(0.5f * (Zj.y + Zm.y), 0.5f * (Zm.x - Zj.x));
            Fq[(size_t)t0 * NF + j] = f0;
            Fq[(size_t)t1 * NF + j] = f1;
        }
    }
}

// ---------------------------------------------------------------------------
// Chunked causal cumsum over s per (b, f), then U = Fmem * conj(Fq) in place.
// ---------------------------------------------------------------------------
__global__ __launch_bounds__(256) void hrr_chunk_sum(const float2* __restrict__ Fkv,
                                                     float2* __restrict__ part) {
    int f = blockIdx.x * 256 + threadIdx.x;
    if (f >= NF) return;
    int ch = blockIdx.y, b = blockIdx.z;
    float sx = 0.f, sy = 0.f;
    size_t base = ((size_t)b * NS + (size_t)ch * CHS) * NF + f;
    for (int i = 0; i < CHS; ++i) {
        float2 t = Fkv[base + (size_t)i * NF];
        sx += t.x; sy += t.y;
    }
    part[(size_t)(b * NCH + ch) * NF + f] = make_float2(sx, sy);
}

__global__ __launch_bounds__(256) void hrr_chunk_scan(float2* __restrict__ part) {
    int g = blockIdx.x * 256 + threadIdx.x;
    if (g >= NB * NF) return;
    int b = g / NF, f = g % NF;
    float rx = 0.f, ry = 0.f;
    for (int ch = 0; ch < NCH; ++ch) {
        size_t idx = (size_t)(b * NCH + ch) * NF + f;
        float2 t = part[idx];
        part[idx] = make_float2(rx, ry);
        rx += t.x; ry += t.y;
    }
}

__global__ __launch_bounds__(256) void hrr_scan_apply(float2* __restrict__ Fkv,
                                                      const float2* __restrict__ Fq,
                                                      const float2* __restrict__ part) {
    int f = blockIdx.x * 256 + threadIdx.x;
    if (f >= NF) return;
    int ch = blockIdx.y, b = blockIdx.z;
    float2 run = part[(size_t)(b * NCH + ch) * NF + f];
    size_t base = ((size_t)b * NS + (size_t)ch * CHS) * NF + f;
    for (int i = 0; i < CHS; ++i) {
        size_t idx = base + (size_t)i * NF;
        float2 kv = Fkv[idx];
        run.x += kv.x; run.y += kv.y;
        float2 q = Fq[idx];
        Fkv[idx] = make_float2(run.x * q.x + run.y * q.y,
                               run.y * q.x - run.x * q.y);
    }
}

// ---------------------------------------------------------------------------
// Paired irfft: block handles tokens (2b, 2b+1). z = x1 + i*x2 where
// x1 = irfft(U1), x2 = irfft(U2). C = conj(U1full) - i*conj(U2full);
// w = FFT(C); x1 = w.x/1024, x2 = -w.y/1024. Writes vhat as bf16.
// ---------------------------------------------------------------------------
__global__ __launch_bounds__(256) void hrr_ifft(const float2* __restrict__ U,
                                                const float2* __restrict__ twg,
                                                unsigned short* __restrict__ vhat) {
    __shared__ __attribute__((aligned(16))) float2 X[1024];
    __shared__ __attribute__((aligned(16))) float2 twL[768];
    const int tid = threadIdx.x;
    const int t0 = blockIdx.x * 2, t1 = t0 + 1;
    for (int i = tid; i < 384; i += 256)
        reinterpret_cast<float4*>(twL)[i] = reinterpret_cast<const float4*>(twg)[i];
    const float2* U1 = U + (size_t)t0 * NF;
    const float2* U2 = U + (size_t)t1 * NF;
#pragma unroll
    for (int c = 0; c < 4; ++c) {
        int j = tid + (c << 8);
        float2 Cv;
        if (j <= 512) {
            float2 u1 = U1[j], u2 = U2[j];
            Cv = make_float2(u1.x - u2.y, -u1.y - u2.x);
        } else {
            int m = 1024 - j;
            float2 u1 = U1[m], u2 = U2[m];
            Cv = make_float2(u1.x + u2.y, u1.y - u2.x);
        }
        X[sw(dr4(j))] = Cv;
    }
    __syncthreads();
    fft1024_r4(X, twL, tid);
    const float invN = 1.0f / 1024.0f;
#pragma unroll
    for (int c = 0; c < 4; ++c) {
        int n = tid + (c << 8);
        float2 w = X[sw(n)];
        vhat[(size_t)t0 * D_DIM + n] = f2bf(w.x * invN);
        vhat[(size_t)t1 * D_DIM + n] = f2bf(-w.y * invN);
    }
}

// ---------------------------------------------------------------------------
extern "C" void kernel_launch(void* const* d_in, const int* in_sizes, int n_in,
                              void* d_out, int out_size, void* d_ws, size_t ws_size,
                              hipStream_t stream) {
    const float* x  = (const float*)d_in[0];
    const float* Wq = (const float*)d_in[1];
    const float* Wk = (const float*)d_in[2];
    const float* Wv = (const float*)d_in[3];
    const float* Wo = (const float*)d_in[4];
    float* out = (float*)d_out;

    char* ws = (char*)d_ws;
    float*  QKV  = (float*) (ws + 0);          // [8192][3072] f32 = 100,663,296 B
    float2* Fkv  = (float2*)(ws + 100663296);  // 33,619,968 B
    float2* Fq   = (float2*)(ws + 134283264);  // 33,619,968 B
    float2* part = (float2*)(ws + 167903232);  // 525,312 B
    unsigned short* Wob = (unsigned short*)(ws + 168428544);  // 2,097,152 B (end 170,525,696)
    // temporal aliases:
    unsigned short* xb   = (unsigned short*)Fkv;   // x bf16; dead before Fkv written
    unsigned short* Wqkv = (unsigned short*)Fq;    // [3072][1024] bf16; dead before Fq written
    unsigned short* vhat = (unsigned short*)QKV;   // QKV f32 dead after hrr_fft_fwd
    float2* twg = part;                            // twiddles; clobbered by chunk_sum -> re-init before ifft

    convert_f32_bf16<<<2048, 256, 0, stream>>>(x,  xb,  NTOK * D_DIM / 4);
    convert_f32_bf16<<<1024, 256, 0, stream>>>(Wq, Wqkv,                   D_DIM * D_DIM / 4);
    convert_f32_bf16<<<1024, 256, 0, stream>>>(Wk, Wqkv + 1024 * 1024,     D_DIM * D_DIM / 4);
    convert_f32_bf16<<<1024, 256, 0, stream>>>(Wv, Wqkv + 2 * 1024 * 1024, D_DIM * D_DIM / 4);
    convert_f32_bf16<<<1024, 256, 0, stream>>>(Wo, Wob, D_DIM * D_DIM / 4);
    twiddle_init<<<3, 256, 0, stream>>>(twg);

    // fused QKV projection: [8192][1024] x [3072][1024]^T -> [8192][3072]
    dim3 gq(NTOK / BM, 3072 / BN);
    gemm_bf16_nt<<<gq, 256, 0, stream>>>(xb, Wqkv, QKV, NTOK, 3072, D_DIM);

    hrr_fft_fwd<<<NTOK / 2, 256, 0, stream>>>(QKV, twg, Fkv, Fq);

    dim3 gs((NF + 255) / 256, NCH, NB);
    hrr_chunk_sum<<<gs, 256, 0, stream>>>(Fkv, part);
    hrr_chunk_scan<<<(NB * NF + 255) / 256, 256, 0, stream>>>(part);
    hrr_scan_apply<<<gs, 256, 0, stream>>>(Fkv, Fq, part);

    twiddle_init<<<3, 256, 0, stream>>>(twg);   // part region reused; rebuild twiddles
    hrr_ifft<<<NTOK / 2, 256, 0, stream>>>(Fkv, twg, vhat);

    dim3 go(NTOK / BM, D_DIM / BN);
    gemm_bf16_nt<<<go, 256, 0, stream>>>(vhat, Wob, out, NTOK, D_DIM, D_DIM);
}

// Round 5
// 184.236 us; speedup vs baseline: 7.0924x; 1.1209x over previous
//
#include <hip/hip_runtime.h>

#define D_DIM 1024
#define NF 513            // rfft bins = D/2+1
#define NB 4              // batch
#define NS 2048           // sequence
#define NTOK (NB * NS)    // 8192 tokens
#define NCH 32            // cumsum chunks
#define CHS (NS / NCH)    // 64 steps per chunk

typedef __attribute__((ext_vector_type(8))) short short8_t;   // 8 bf16 = 4 VGPRs
typedef __attribute__((ext_vector_type(4))) float f32x4;

__device__ inline unsigned short f2bf(float f) {
    unsigned u = __builtin_bit_cast(unsigned, f);
    u += 0x7FFFu + ((u >> 16) & 1u);   // round-to-nearest-even
    return (unsigned short)(u >> 16);
}
__device__ inline float bf2f(unsigned short h) {
    unsigned u = ((unsigned)h) << 16;
    return __builtin_bit_cast(float, u);
}
__device__ inline unsigned pkc(float re, float im) {   // packed bf16 complex
    return (unsigned)f2bf(re) | ((unsigned)f2bf(im) << 16);
}
__device__ inline float2 upc(unsigned u) {
    return make_float2(bf2f((unsigned short)(u & 0xFFFFu)), bf2f((unsigned short)(u >> 16)));
}

__global__ __launch_bounds__(256) void convert_x(const float* __restrict__ src,
                                                 unsigned short* __restrict__ dst,
                                                 int n4) {
    int i = blockIdx.x * 256 + threadIdx.x;
    int stride = gridDim.x * 256;
    for (; i < n4; i += stride) {
        float4 v = reinterpret_cast<const float4*>(src)[i];
        ushort4 o;
        o.x = f2bf(v.x); o.y = f2bf(v.y); o.z = f2bf(v.z); o.w = f2bf(v.w);
        reinterpret_cast<ushort4*>(dst)[i] = o;
    }
}

// all four weights in one dispatch: gridDim.y selects the weight
__global__ __launch_bounds__(256) void convert_w(const float* __restrict__ Wq,
                                                 const float* __restrict__ Wk,
                                                 const float* __restrict__ Wv,
                                                 const float* __restrict__ Wo,
                                                 unsigned short* __restrict__ Wqkv,
                                                 unsigned short* __restrict__ Wob) {
    int y = blockIdx.y;
    const float* src = (y == 0) ? Wq : (y == 1) ? Wk : (y == 2) ? Wv : Wo;
    unsigned short* dst = (y < 3) ? (Wqkv + (size_t)y * 1048576) : Wob;
    int i = blockIdx.x * 256 + threadIdx.x;   // exactly 1024 blocks * 256 = 262144 float4s
    float4 v = reinterpret_cast<const float4*>(src)[i];
    ushort4 o;
    o.x = f2bf(v.x); o.y = f2bf(v.y); o.z = f2bf(v.z); o.w = f2bf(v.w);
    reinterpret_cast<ushort4*>(dst)[i] = o;
}

// ---------------------------------------------------------------------------
// bf16 MFMA GEMM: C[M,N] = A[M,K] * B[N,K]^T.  128x128 tile, BK=32.
// OutT = float (fp32 C) or unsigned short (bf16 C).
// ---------------------------------------------------------------------------
#define BM 128
#define BN 128
#define BK 32

__device__ inline void gload_lds16(const void* g, void* l) {
    __builtin_amdgcn_global_load_lds(
        (const __attribute__((address_space(1))) void*)g,
        (__attribute__((address_space(3))) void*)l,
        16, 0, 0);
}

template <typename OutT>
__global__ __launch_bounds__(256) void gemm_bf16_nt(const unsigned short* __restrict__ A,
                                                    const unsigned short* __restrict__ B,
                                                    OutT* __restrict__ C,
                                                    int M, int N, int K) {
    __shared__ __attribute__((aligned(16))) unsigned short ldsA[BM * BK];
    __shared__ __attribute__((aligned(16))) unsigned short ldsB[BN * BK];
    const int tid  = threadIdx.x;
    const int wave = tid >> 6;
    const int lane = tid & 63;
    const int l15  = lane & 15;
    const int k8   = (lane >> 4) << 3;
    const int wm   = (wave >> 1) * 64;
    const int wn   = (wave & 1) * 64;
    const int bm   = blockIdx.x * BM;
    const int bn   = blockIdx.y * BN;
    const int crow = tid >> 2;
    const int ccol = (tid & 3) << 3;

    f32x4 acc[4][4];
#pragma unroll
    for (int i = 0; i < 4; ++i)
#pragma unroll
        for (int j = 0; j < 4; ++j)
            acc[i][j] = (f32x4){0.f, 0.f, 0.f, 0.f};

    for (int k0 = 0; k0 < K; k0 += BK) {
        __syncthreads();
#pragma unroll
        for (int c = 0; c < 2; ++c) {
            int row = crow + (c << 6);
            gload_lds16(A + (size_t)(bm + row) * K + k0 + ccol, &ldsA[row * BK + ccol]);
            gload_lds16(B + (size_t)(bn + row) * K + k0 + ccol, &ldsB[row * BK + ccol]);
        }
        __syncthreads();

        short8_t af[4], bf[4];
#pragma unroll
        for (int mi = 0; mi < 4; ++mi)
            af[mi] = *reinterpret_cast<const short8_t*>(&ldsA[(wm + mi * 16 + l15) * BK + k8]);
#pragma unroll
        for (int ni = 0; ni < 4; ++ni)
            bf[ni] = *reinterpret_cast<const short8_t*>(&ldsB[(wn + ni * 16 + l15) * BK + k8]);
#pragma unroll
        for (int mi = 0; mi < 4; ++mi)
#pragma unroll
            for (int ni = 0; ni < 4; ++ni)
                acc[mi][ni] = __builtin_amdgcn_mfma_f32_16x16x32_bf16(af[mi], bf[ni], acc[mi][ni], 0, 0, 0);
    }

#pragma unroll
    for (int mi = 0; mi < 4; ++mi) {
        int rbase = bm + wm + mi * 16 + (lane >> 4) * 4;
#pragma unroll
        for (int ni = 0; ni < 4; ++ni) {
            int col = bn + wn + ni * 16 + l15;
#pragma unroll
            for (int j = 0; j < 4; ++j) {
                float v = acc[mi][ni][j];
                if constexpr (sizeof(OutT) == 4)
                    C[(size_t)(rbase + j) * N + col] = v;
                else
                    C[(size_t)(rbase + j) * N + col] = f2bf(v);
            }
        }
    }
}

// ---------------------------------------------------------------------------
// Radix-4 1024-pt complex FFT in LDS, float2 elements, XOR bank swizzle.
// ---------------------------------------------------------------------------
__device__ inline int sw(int i) { return i ^ ((i >> 4) & 15); }

__device__ inline int dr4(int n) {   // reverse 5 base-4 digits of 10-bit n
    return ((n & 3) << 8) | (((n >> 2) & 3) << 6) | (((n >> 4) & 3) << 4) |
           (((n >> 6) & 3) << 2) | ((n >> 8) & 3);
}

__device__ inline float2 cmul(float2 a, float2 b) {
    return make_float2(a.x * b.x - a.y * b.y, a.x * b.y + a.y * b.x);
}

__device__ inline void fft1024_r4(float2* X, const float2* tw, int t) {
#pragma unroll
    for (int s = 0; s < 5; ++s) {
        const int L = 1 << (2 * s);
        const int r = t & (L - 1);
        const int base = ((t >> (2 * s)) << (2 * s + 2)) + r;
        float2 A  = X[sw(base)];
        float2 Bv = X[sw(base + L)];
        float2 Cv = X[sw(base + 2 * L)];
        float2 Dv = X[sw(base + 3 * L)];
        if (s != 0) {
            const int step = 1024 >> (2 * s + 2);
            Bv = cmul(Bv, tw[sw(r * step)]);
            Cv = cmul(Cv, tw[sw(2 * r * step)]);
            Dv = cmul(Dv, tw[sw(3 * r * step)]);
        }
        float2 e0 = make_float2(A.x + Cv.x, A.y + Cv.y);
        float2 e1 = make_float2(A.x - Cv.x, A.y - Cv.y);
        float2 o0 = make_float2(Bv.x + Dv.x, Bv.y + Dv.y);
        float2 o1 = make_float2(Bv.x - Dv.x, Bv.y - Dv.y);
        X[sw(base)]         = make_float2(e0.x + o0.x, e0.y + o0.y);
        X[sw(base + L)]     = make_float2(e1.x + o1.y, e1.y - o1.x);
        X[sw(base + 2 * L)] = make_float2(e0.x - o0.x, e0.y - o0.y);
        X[sw(base + 3 * L)] = make_float2(e1.x - o1.y, e1.y + o1.x);
        __syncthreads();
    }
}

__global__ __launch_bounds__(256) void twiddle_init(float2* __restrict__ twg) {
    int k = blockIdx.x * 256 + threadIdx.x;
    if (k < 768) {
        float ang = -6.283185307179586f * (float)k / 1024.0f;
        float s, c;
        sincosf(ang, &s, &c);
        twg[sw(k)] = make_float2(c, s);
    }
}

// ---------------------------------------------------------------------------
// Forward: block handles tokens (2b, 2b+1). QKV is bf16 [tok][3072] = q|k|v.
// Outputs packed-bf16 complex Fkv, Fq.
// ---------------------------------------------------------------------------
__global__ __launch_bounds__(256) void hrr_fft_fwd(const unsigned short* __restrict__ QKV,
                                                   const float2* __restrict__ twg,
                                                   unsigned* __restrict__ Fkv,
                                                   unsigned* __restrict__ Fq) {
    __shared__ __attribute__((aligned(16))) float2 X[1024];
    __shared__ __attribute__((aligned(16))) float2 twL[768];
    const int tid = threadIdx.x;
    const int t0 = blockIdx.x * 2, t1 = t0 + 1;
    for (int i = tid; i < 384; i += 256)
        reinterpret_cast<float4*>(twL)[i] = reinterpret_cast<const float4*>(twg)[i];

#pragma unroll
    for (int which = 0; which < 2; ++which) {
        const int tok = which ? t1 : t0;
        const ushort4* Kr = (const ushort4*)(QKV + (size_t)tok * 3072 + 1024);
        const ushort4* Vr = (const ushort4*)(QKV + (size_t)tok * 3072 + 2048);
        ushort4 k4 = Kr[tid], v4 = Vr[tid];
        X[sw(dr4(4 * tid + 0))] = make_float2(bf2f(k4.x), bf2f(v4.x));
        X[sw(dr4(4 * tid + 1))] = make_float2(bf2f(k4.y), bf2f(v4.y));
        X[sw(dr4(4 * tid + 2))] = make_float2(bf2f(k4.z), bf2f(v4.z));
        X[sw(dr4(4 * tid + 3))] = make_float2(bf2f(k4.w), bf2f(v4.w));
        __syncthreads();
        fft1024_r4(X, twL, tid);
        for (int j = tid; j < NF; j += 256) {
            float2 Zj = X[sw(j)];
            float2 Zm = X[sw((1024 - j) & 1023)];
            float2 Fk = make_float2(0.5f * (Zj.x + Zm.x), 0.5f * (Zj.y - Zm.y));
            float2 Fv = make_float2(0.5f * (Zj.y + Zm.y), 0.5f * (Zm.x - Zj.x));
            float2 p = cmul(Fk, Fv);
            Fkv[(size_t)tok * NF + j] = pkc(p.x, p.y);
        }
        __syncthreads();
    }
    // Q pair
    {
        const ushort4* Q0 = (const ushort4*)(QKV + (size_t)t0 * 3072);
        const ushort4* Q1 = (const ushort4*)(QKV + (size_t)t1 * 3072);
        ushort4 a4 = Q0[tid], b4 = Q1[tid];
        X[sw(dr4(4 * tid + 0))] = make_float2(bf2f(a4.x), bf2f(b4.x));
        X[sw(dr4(4 * tid + 1))] = make_float2(bf2f(a4.y), bf2f(b4.y));
        X[sw(dr4(4 * tid + 2))] = make_float2(bf2f(a4.z), bf2f(b4.z));
        X[sw(dr4(4 * tid + 3))] = make_float2(bf2f(a4.w), bf2f(b4.w));
        __syncthreads();
        fft1024_r4(X, twL, tid);
        for (int j = tid; j < NF; j += 256) {
            float2 Zj = X[sw(j)];
            float2 Zm = X[sw((1024 - j) & 1023)];
            Fq[(size_t)t0 * NF + j] = pkc(0.5f * (Zj.x + Zm.x), 0.5f * (Zj.y - Zm.y));
            Fq[(size_t)t1 * NF + j] = pkc(0.5f * (Zj.y + Zm.y), 0.5f * (Zm.x - Zj.x));
        }
    }
}

// ---------------------------------------------------------------------------
// Chunked causal cumsum (fp32 accumulation over bf16 terms).
// ---------------------------------------------------------------------------
__global__ __launch_bounds__(256) void hrr_chunk_sum(const unsigned* __restrict__ Fkv,
                                                     float2* __restrict__ part) {
    int f = blockIdx.x * 256 + threadIdx.x;
    if (f >= NF) return;
    int ch = blockIdx.y, b = blockIdx.z;
    float sx = 0.f, sy = 0.f;
    size_t base = ((size_t)b * NS + (size_t)ch * CHS) * NF + f;
    for (int i = 0; i < CHS; ++i) {
        float2 t = upc(Fkv[base + (size_t)i * NF]);
        sx += t.x; sy += t.y;
    }
    part[(size_t)(b * NCH + ch) * NF + f] = make_float2(sx, sy);
}

// exclusive prefix of chunk totals computed inline (part is small + L2-hot),
// then running cumsum * conj(Fq) -> U, written in place over Fkv (bf16).
__global__ __launch_bounds__(256) void hrr_scan_apply(unsigned* __restrict__ Fkv,
                                                      const unsigned* __restrict__ Fq,
                                                      const float2* __restrict__ part) {
    int f = blockIdx.x * 256 + threadIdx.x;
    if (f >= NF) return;
    int ch = blockIdx.y, b = blockIdx.z;
    float rx = 0.f, ry = 0.f;
    for (int c2 = 0; c2 < ch; ++c2) {
        float2 p = part[(size_t)(b * NCH + c2) * NF + f];
        rx += p.x; ry += p.y;
    }
    size_t base = ((size_t)b * NS + (size_t)ch * CHS) * NF + f;
    for (int i = 0; i < CHS; ++i) {
        size_t idx = base + (size_t)i * NF;
        float2 kv = upc(Fkv[idx]);
        rx += kv.x; ry += kv.y;
        float2 q = upc(Fq[idx]);
        Fkv[idx] = pkc(rx * q.x + ry * q.y, ry * q.x - rx * q.y);
    }
}

// ---------------------------------------------------------------------------
// Paired irfft of bf16 U; writes vhat bf16.
// ---------------------------------------------------------------------------
__global__ __launch_bounds__(256) void hrr_ifft(const unsigned* __restrict__ U,
                                                const float2* __restrict__ twg,
                                                unsigned short* __restrict__ vhat) {
    __shared__ __attribute__((aligned(16))) float2 X[1024];
    __shared__ __attribute__((aligned(16))) float2 twL[768];
    const int tid = threadIdx.x;
    const int t0 = blockIdx.x * 2, t1 = t0 + 1;
    for (int i = tid; i < 384; i += 256)
        reinterpret_cast<float4*>(twL)[i] = reinterpret_cast<const float4*>(twg)[i];
    const unsigned* U1 = U + (size_t)t0 * NF;
    const unsigned* U2 = U + (size_t)t1 * NF;
#pragma unroll
    for (int c = 0; c < 4; ++c) {
        int j = tid + (c << 8);
        float2 Cv;
        if (j <= 512) {
            float2 u1 = upc(U1[j]), u2 = upc(U2[j]);
            Cv = make_float2(u1.x - u2.y, -u1.y - u2.x);
        } else {
            int m = 1024 - j;
            float2 u1 = upc(U1[m]), u2 = upc(U2[m]);
            Cv = make_float2(u1.x + u2.y, u1.y - u2.x);
        }
        X[sw(dr4(j))] = Cv;
    }
    __syncthreads();
    fft1024_r4(X, twL, tid);
    const float invN = 1.0f / 1024.0f;
#pragma unroll
    for (int c = 0; c < 4; ++c) {
        int n = tid + (c << 8);
        float2 w = X[sw(n)];
        vhat[(size_t)t0 * D_DIM + n] = f2bf(w.x * invN);
        vhat[(size_t)t1 * D_DIM + n] = f2bf(-w.y * invN);
    }
}

// ---------------------------------------------------------------------------
extern "C" void kernel_launch(void* const* d_in, const int* in_sizes, int n_in,
                              void* d_out, int out_size, void* d_ws, size_t ws_size,
                              hipStream_t stream) {
    const float* x  = (const float*)d_in[0];
    const float* Wq = (const float*)d_in[1];
    const float* Wk = (const float*)d_in[2];
    const float* Wv = (const float*)d_in[3];
    const float* Wo = (const float*)d_in[4];
    float* out = (float*)d_out;

    char* ws = (char*)d_ws;
    unsigned short* QKVb = (unsigned short*)(ws + 0);          // 50,331,648 B
    unsigned*       Fkv  = (unsigned*)      (ws + 50331648);   // 16,809,984 B
    unsigned*       Fq   = (unsigned*)      (ws + 67141632);   // 16,809,984 B
    float2*         part = (float2*)        (ws + 83951616);   //    525,312 B
    float2*         twg  = (float2*)        (ws + 84476928);   //      6,144 B
    unsigned short* Wob  = (unsigned short*)(ws + 84483072);   //  2,097,152 B
    unsigned short* Wqkv = (unsigned short*)(ws + 86580224);   //  6,291,456 B
    unsigned short* xb   = (unsigned short*)(ws + 92871680);   // 16,777,216 B
    unsigned short* vhat = (unsigned short*)(ws + 109648896);  // 16,777,216 B (end ~126.4 MB)

    convert_x<<<2048, 256, 0, stream>>>(x, xb, NTOK * D_DIM / 4);
    convert_w<<<dim3(1024, 4), 256, 0, stream>>>(Wq, Wk, Wv, Wo, Wqkv, Wob);
    twiddle_init<<<3, 256, 0, stream>>>(twg);

    dim3 gq(NTOK / BM, 3072 / BN);
    gemm_bf16_nt<unsigned short><<<gq, 256, 0, stream>>>(xb, Wqkv, QKVb, NTOK, 3072, D_DIM);

    hrr_fft_fwd<<<NTOK / 2, 256, 0, stream>>>(QKVb, twg, Fkv, Fq);

    dim3 gs((NF + 255) / 256, NCH, NB);
    hrr_chunk_sum<<<gs, 256, 0, stream>>>(Fkv, part);
    hrr_scan_apply<<<gs, 256, 0, stream>>>(Fkv, Fq, part);

    hrr_ifft<<<NTOK / 2, 256, 0, stream>>>(Fkv, twg, vhat);

    dim3 go(NTOK / BM, D_DIM / BN);
    gemm_bf16_nt<float><<<go, 256, 0, stream>>>(vhat, Wob, out, NTOK, D_DIM, D_DIM);
}

// Round 6
// 175.597 us; speedup vs baseline: 7.4413x; 1.0492x over previous
//
#include <hip/hip_runtime.h>

#define D_DIM 1024
#define NF 513            // rfft bins = D/2+1
#define NB 4              // batch
#define NS 2048           // sequence
#define NTOK (NB * NS)    // 8192 tokens
#define NCH 32            // cumsum chunks
#define CHS (NS / NCH)    // 64 steps per chunk

typedef __attribute__((ext_vector_type(8))) short short8_t;   // 8 bf16 = 4 VGPRs
typedef __attribute__((ext_vector_type(4))) float f32x4;

__device__ inline unsigned short f2bf(float f) {
    unsigned u = __builtin_bit_cast(unsigned, f);
    u += 0x7FFFu + ((u >> 16) & 1u);   // round-to-nearest-even
    return (unsigned short)(u >> 16);
}
__device__ inline float bf2f(unsigned short h) {
    unsigned u = ((unsigned)h) << 16;
    return __builtin_bit_cast(float, u);
}
__device__ inline unsigned pkc(float re, float im) {   // packed bf16 complex
    return (unsigned)f2bf(re) | ((unsigned)f2bf(im) << 16);
}
__device__ inline float2 upc(unsigned u) {
    return make_float2(bf2f((unsigned short)(u & 0xFFFFu)), bf2f((unsigned short)(u >> 16)));
}

__global__ __launch_bounds__(256) void convert_x(const float* __restrict__ src,
                                                 unsigned short* __restrict__ dst,
                                                 int n4) {
    int i = blockIdx.x * 256 + threadIdx.x;
    int stride = gridDim.x * 256;
    for (; i < n4; i += stride) {
        float4 v = reinterpret_cast<const float4*>(src)[i];
        ushort4 o;
        o.x = f2bf(v.x); o.y = f2bf(v.y); o.z = f2bf(v.z); o.w = f2bf(v.w);
        reinterpret_cast<ushort4*>(dst)[i] = o;
    }
}

// all four weights in one dispatch: gridDim.y selects the weight
__global__ __launch_bounds__(256) void convert_w(const float* __restrict__ Wq,
                                                 const float* __restrict__ Wk,
                                                 const float* __restrict__ Wv,
                                                 const float* __restrict__ Wo,
                                                 unsigned short* __restrict__ Wqkv,
                                                 unsigned short* __restrict__ Wob) {
    int y = blockIdx.y;
    const float* src = (y == 0) ? Wq : (y == 1) ? Wk : (y == 2) ? Wv : Wo;
    unsigned short* dst = (y < 3) ? (Wqkv + (size_t)y * 1048576) : Wob;
    int i = blockIdx.x * 256 + threadIdx.x;
    float4 v = reinterpret_cast<const float4*>(src)[i];
    ushort4 o;
    o.x = f2bf(v.x); o.y = f2bf(v.y); o.z = f2bf(v.z); o.w = f2bf(v.w);
    reinterpret_cast<ushort4*>(dst)[i] = o;
}

// ---------------------------------------------------------------------------
// bf16 MFMA GEMM: C[M,N] = A[M,K] * B[N,K]^T.  128x128 tile, BK=32.
// 3-buffer LDS pipeline, 2-tile stage lead, counted vmcnt (never 0 in steady
// state): loads stay in flight across raw s_barrier (no __syncthreads drain).
// Per-wave per-tile staging = 4 global_load_lds insts -> vmcnt(8) = 2 tiles.
// ---------------------------------------------------------------------------
#define BM 128
#define BN 128
#define BK 32

__device__ inline void gload_lds16(const void* g, void* l) {
    __builtin_amdgcn_global_load_lds(
        (const __attribute__((address_space(1))) void*)g,
        (__attribute__((address_space(3))) void*)l,
        16, 0, 0);
}

template <typename OutT>
__global__ __launch_bounds__(256) void gemm_bf16_nt(const unsigned short* __restrict__ A,
                                                    const unsigned short* __restrict__ B,
                                                    OutT* __restrict__ C,
                                                    int M, int N, int K) {
    // 3 rotating buffers: [buf][BM*BK] for A, same for B.  48 KiB total.
    __shared__ __attribute__((aligned(16))) unsigned short ldsA[3 * BM * BK];
    __shared__ __attribute__((aligned(16))) unsigned short ldsB[3 * BN * BK];
    const int tid  = threadIdx.x;
    const int wave = tid >> 6;
    const int lane = tid & 63;
    const int l15  = lane & 15;
    const int k8   = (lane >> 4) << 3;
    const int wm   = (wave >> 1) * 64;
    const int wn   = (wave & 1) * 64;
    const int bm   = blockIdx.x * BM;
    const int bn   = blockIdx.y * BN;
    const int crow = tid >> 2;               // staging row: 0..63 (c adds 64)
    const int ccol = (tid & 3) << 3;         // staging k-offset: 0,8,16,24
    const int NT   = K / BK;

    const unsigned short* Arow = A + (size_t)(bm + crow) * K + ccol;
    const unsigned short* Brow = B + (size_t)(bn + crow) * K + ccol;
    const size_t rstep = (size_t)64 * K;     // c=1 row offset

    f32x4 acc[4][4];
#pragma unroll
    for (int i = 0; i < 4; ++i)
#pragma unroll
        for (int j = 0; j < 4; ++j)
            acc[i][j] = (f32x4){0.f, 0.f, 0.f, 0.f};

    // STAGE(tile t -> buffer b): 4 global_load_lds instructions per wave.
    auto STAGE = [&](int t, int b) {
        const int k0 = t * BK;
        unsigned short* la = &ldsA[b * (BM * BK) + crow * BK + ccol];
        unsigned short* lb = &ldsB[b * (BM * BK) + crow * BK + ccol];
        gload_lds16(Arow + k0, la);
        gload_lds16(Brow + k0, lb);
        gload_lds16(Arow + rstep + k0, la + 64 * BK);
        gload_lds16(Brow + rstep + k0, lb + 64 * BK);
    };

    STAGE(0, 0);
    STAGE(1, 1);

    for (int j = 0; j < NT; ++j) {
        const int buf = j % 3;
        if (j + 2 < NT) STAGE(j + 2, (j + 2) % 3);

        // counted wait: ensure tile j's 4 loads landed (per wave), leaving up
        // to 2 tiles (8 insts) in flight.  Tail drains 4 -> 0.
        if (j + 2 < NT)      asm volatile("s_waitcnt vmcnt(8)" ::: "memory");
        else if (j + 1 < NT) asm volatile("s_waitcnt vmcnt(4)" ::: "memory");
        else                 asm volatile("s_waitcnt vmcnt(0)" ::: "memory");
        __builtin_amdgcn_s_barrier();           // all waves' tile-j loads visible
        asm volatile("" ::: "memory");          // pin LDS reads below barrier

        const unsigned short* la = &ldsA[buf * (BM * BK)];
        const unsigned short* lb = &ldsB[buf * (BM * BK)];
        short8_t af[4], bfv[4];
#pragma unroll
        for (int mi = 0; mi < 4; ++mi)
            af[mi] = *reinterpret_cast<const short8_t*>(&la[(wm + mi * 16 + l15) * BK + k8]);
#pragma unroll
        for (int ni = 0; ni < 4; ++ni)
            bfv[ni] = *reinterpret_cast<const short8_t*>(&lb[(wn + ni * 16 + l15) * BK + k8]);

        __builtin_amdgcn_s_setprio(1);
#pragma unroll
        for (int mi = 0; mi < 4; ++mi)
#pragma unroll
            for (int ni = 0; ni < 4; ++ni)
                acc[mi][ni] = __builtin_amdgcn_mfma_f32_16x16x32_bf16(af[mi], bfv[ni], acc[mi][ni], 0, 0, 0);
        __builtin_amdgcn_s_setprio(0);

        __builtin_amdgcn_s_barrier();           // reads done before buf reuse
        asm volatile("" ::: "memory");          // pin next STAGE below barrier
    }

#pragma unroll
    for (int mi = 0; mi < 4; ++mi) {
        int rbase = bm + wm + mi * 16 + (lane >> 4) * 4;
#pragma unroll
        for (int ni = 0; ni < 4; ++ni) {
            int col = bn + wn + ni * 16 + l15;
#pragma unroll
            for (int j = 0; j < 4; ++j) {
                float v = acc[mi][ni][j];
                if constexpr (sizeof(OutT) == 4)
                    C[(size_t)(rbase + j) * N + col] = v;
                else
                    C[(size_t)(rbase + j) * N + col] = f2bf(v);
            }
        }
    }
}

// ---------------------------------------------------------------------------
// Radix-4 1024-pt complex FFT in LDS, float2 elements, XOR bank swizzle.
// ---------------------------------------------------------------------------
__device__ inline int sw(int i) { return i ^ ((i >> 4) & 15); }

__device__ inline int dr4(int n) {   // reverse 5 base-4 digits of 10-bit n
    return ((n & 3) << 8) | (((n >> 2) & 3) << 6) | (((n >> 4) & 3) << 4) |
           (((n >> 6) & 3) << 2) | ((n >> 8) & 3);
}

__device__ inline float2 cmul(float2 a, float2 b) {
    return make_float2(a.x * b.x - a.y * b.y, a.x * b.y + a.y * b.x);
}

__device__ inline void fft1024_r4(float2* X, const float2* tw, int t) {
#pragma unroll
    for (int s = 0; s < 5; ++s) {
        const int L = 1 << (2 * s);
        const int r = t & (L - 1);
        const int base = ((t >> (2 * s)) << (2 * s + 2)) + r;
        float2 A  = X[sw(base)];
        float2 Bv = X[sw(base + L)];
        float2 Cv = X[sw(base + 2 * L)];
        float2 Dv = X[sw(base + 3 * L)];
        if (s != 0) {
            const int step = 1024 >> (2 * s + 2);
            Bv = cmul(Bv, tw[sw(r * step)]);
            Cv = cmul(Cv, tw[sw(2 * r * step)]);
            Dv = cmul(Dv, tw[sw(3 * r * step)]);
        }
        float2 e0 = make_float2(A.x + Cv.x, A.y + Cv.y);
        float2 e1 = make_float2(A.x - Cv.x, A.y - Cv.y);
        float2 o0 = make_float2(Bv.x + Dv.x, Bv.y + Dv.y);
        float2 o1 = make_float2(Bv.x - Dv.x, Bv.y - Dv.y);
        X[sw(base)]         = make_float2(e0.x + o0.x, e0.y + o0.y);
        X[sw(base + L)]     = make_float2(e1.x + o1.y, e1.y - o1.x);
        X[sw(base + 2 * L)] = make_float2(e0.x - o0.x, e0.y - o0.y);
        X[sw(base + 3 * L)] = make_float2(e1.x - o1.y, e1.y + o1.x);
        __syncthreads();
    }
}

__global__ __launch_bounds__(256) void twiddle_init(float2* __restrict__ twg) {
    int k = blockIdx.x * 256 + threadIdx.x;
    if (k < 768) {
        float ang = -6.283185307179586f * (float)k / 1024.0f;
        float s, c;
        sincosf(ang, &s, &c);
        twg[sw(k)] = make_float2(c, s);
    }
}

// ---------------------------------------------------------------------------
// Forward: block handles tokens (2b, 2b+1). QKV is bf16 [tok][3072] = q|k|v.
// Outputs packed-bf16 complex Fkv, Fq.
// ---------------------------------------------------------------------------
__global__ __launch_bounds__(256) void hrr_fft_fwd(const unsigned short* __restrict__ QKV,
                                                   const float2* __restrict__ twg,
                                                   unsigned* __restrict__ Fkv,
                                                   unsigned* __restrict__ Fq) {
    __shared__ __attribute__((aligned(16))) float2 X[1024];
    __shared__ __attribute__((aligned(16))) float2 twL[768];
    const int tid = threadIdx.x;
    const int t0 = blockIdx.x * 2, t1 = t0 + 1;
    for (int i = tid; i < 384; i += 256)
        reinterpret_cast<float4*>(twL)[i] = reinterpret_cast<const float4*>(twg)[i];

#pragma unroll
    for (int which = 0; which < 2; ++which) {
        const int tok = which ? t1 : t0;
        const ushort4* Kr = (const ushort4*)(QKV + (size_t)tok * 3072 + 1024);
        const ushort4* Vr = (const ushort4*)(QKV + (size_t)tok * 3072 + 2048);
        ushort4 k4 = Kr[tid], v4 = Vr[tid];
        X[sw(dr4(4 * tid + 0))] = make_float2(bf2f(k4.x), bf2f(v4.x));
        X[sw(dr4(4 * tid + 1))] = make_float2(bf2f(k4.y), bf2f(v4.y));
        X[sw(dr4(4 * tid + 2))] = make_float2(bf2f(k4.z), bf2f(v4.z));
        X[sw(dr4(4 * tid + 3))] = make_float2(bf2f(k4.w), bf2f(v4.w));
        __syncthreads();
        fft1024_r4(X, twL, tid);
        for (int j = tid; j < NF; j += 256) {
            float2 Zj = X[sw(j)];
            float2 Zm = X[sw((1024 - j) & 1023)];
            float2 Fk = make_float2(0.5f * (Zj.x + Zm.x), 0.5f * (Zj.y - Zm.y));
            float2 Fv = make_float2(0.5f * (Zj.y + Zm.y), 0.5f * (Zm.x - Zj.x));
            float2 p = cmul(Fk, Fv);
            Fkv[(size_t)tok * NF + j] = pkc(p.x, p.y);
        }
        __syncthreads();
    }
    // Q pair
    {
        const ushort4* Q0 = (const ushort4*)(QKV + (size_t)t0 * 3072);
        const ushort4* Q1 = (const ushort4*)(QKV + (size_t)t1 * 3072);
        ushort4 a4 = Q0[tid], b4 = Q1[tid];
        X[sw(dr4(4 * tid + 0))] = make_float2(bf2f(a4.x), bf2f(b4.x));
        X[sw(dr4(4 * tid + 1))] = make_float2(bf2f(a4.y), bf2f(b4.y));
        X[sw(dr4(4 * tid + 2))] = make_float2(bf2f(a4.z), bf2f(b4.z));
        X[sw(dr4(4 * tid + 3))] = make_float2(bf2f(a4.w), bf2f(b4.w));
        __syncthreads();
        fft1024_r4(X, twL, tid);
        for (int j = tid; j < NF; j += 256) {
            float2 Zj = X[sw(j)];
            float2 Zm = X[sw((1024 - j) & 1023)];
            Fq[(size_t)t0 * NF + j] = pkc(0.5f * (Zj.x + Zm.x), 0.5f * (Zj.y - Zm.y));
            Fq[(size_t)t1 * NF + j] = pkc(0.5f * (Zj.y + Zm.y), 0.5f * (Zm.x - Zj.x));
        }
    }
}

// ---------------------------------------------------------------------------
// Chunked causal cumsum (fp32 accumulation over bf16 terms).
// ---------------------------------------------------------------------------
__global__ __launch_bounds__(256) void hrr_chunk_sum(const unsigned* __restrict__ Fkv,
                                                     float2* __restrict__ part) {
    int f = blockIdx.x * 256 + threadIdx.x;
    if (f >= NF) return;
    int ch = blockIdx.y, b = blockIdx.z;
    float sx = 0.f, sy = 0.f;
    size_t base = ((size_t)b * NS + (size_t)ch * CHS) * NF + f;
    for (int i = 0; i < CHS; ++i) {
        float2 t = upc(Fkv[base + (size_t)i * NF]);
        sx += t.x; sy += t.y;
    }
    part[(size_t)(b * NCH + ch) * NF + f] = make_float2(sx, sy);
}

// exclusive prefix of chunk totals computed inline (part is small + L2-hot),
// then running cumsum * conj(Fq) -> U, written in place over Fkv (bf16).
__global__ __launch_bounds__(256) void hrr_scan_apply(unsigned* __restrict__ Fkv,
                                                      const unsigned* __restrict__ Fq,
                                                      const float2* __restrict__ part) {
    int f = blockIdx.x * 256 + threadIdx.x;
    if (f >= NF) return;
    int ch = blockIdx.y, b = blockIdx.z;
    float rx = 0.f, ry = 0.f;
    for (int c2 = 0; c2 < ch; ++c2) {
        float2 p = part[(size_t)(b * NCH + c2) * NF + f];
        rx += p.x; ry += p.y;
    }
    size_t base = ((size_t)b * NS + (size_t)ch * CHS) * NF + f;
    for (int i = 0; i < CHS; ++i) {
        size_t idx = base + (size_t)i * NF;
        float2 kv = upc(Fkv[idx]);
        rx += kv.x; ry += kv.y;
        float2 q = upc(Fq[idx]);
        Fkv[idx] = pkc(rx * q.x + ry * q.y, ry * q.x - rx * q.y);
    }
}

// ---------------------------------------------------------------------------
// Paired irfft of bf16 U; writes vhat bf16.
// ---------------------------------------------------------------------------
__global__ __launch_bounds__(256) void hrr_ifft(const unsigned* __restrict__ U,
                                                const float2* __restrict__ twg,
                                                unsigned short* __restrict__ vhat) {
    __shared__ __attribute__((aligned(16))) float2 X[1024];
    __shared__ __attribute__((aligned(16))) float2 twL[768];
    const int tid = threadIdx.x;
    const int t0 = blockIdx.x * 2, t1 = t0 + 1;
    for (int i = tid; i < 384; i += 256)
        reinterpret_cast<float4*>(twL)[i] = reinterpret_cast<const float4*>(twg)[i];
    const unsigned* U1 = U + (size_t)t0 * NF;
    const unsigned* U2 = U + (size_t)t1 * NF;
#pragma unroll
    for (int c = 0; c < 4; ++c) {
        int j = tid + (c << 8);
        float2 Cv;
        if (j <= 512) {
            float2 u1 = upc(U1[j]), u2 = upc(U2[j]);
            Cv = make_float2(u1.x - u2.y, -u1.y - u2.x);
        } else {
            int m = 1024 - j;
            float2 u1 = upc(U1[m]), u2 = upc(U2[m]);
            Cv = make_float2(u1.x + u2.y, u1.y - u2.x);
        }
        X[sw(dr4(j))] = Cv;
    }
    __syncthreads();
    fft1024_r4(X, twL, tid);
    const float invN = 1.0f / 1024.0f;
#pragma unroll
    for (int c = 0; c < 4; ++c) {
        int n = tid + (c << 8);
        float2 w = X[sw(n)];
        vhat[(size_t)t0 * D_DIM + n] = f2bf(w.x * invN);
        vhat[(size_t)t1 * D_DIM + n] = f2bf(-w.y * invN);
    }
}

// ---------------------------------------------------------------------------
extern "C" void kernel_launch(void* const* d_in, const int* in_sizes, int n_in,
                              void* d_out, int out_size, void* d_ws, size_t ws_size,
                              hipStream_t stream) {
    const float* x  = (const float*)d_in[0];
    const float* Wq = (const float*)d_in[1];
    const float* Wk = (const float*)d_in[2];
    const float* Wv = (const float*)d_in[3];
    const float* Wo = (const float*)d_in[4];
    float* out = (float*)d_out;

    char* ws = (char*)d_ws;
    unsigned short* QKVb = (unsigned short*)(ws + 0);          // 50,331,648 B
    unsigned*       Fkv  = (unsigned*)      (ws + 50331648);   // 16,809,984 B
    unsigned*       Fq   = (unsigned*)      (ws + 67141632);   // 16,809,984 B
    float2*         part = (float2*)        (ws + 83951616);   //    525,312 B
    float2*         twg  = (float2*)        (ws + 84476928);   //      6,144 B
    unsigned short* Wob  = (unsigned short*)(ws + 84483072);   //  2,097,152 B
    unsigned short* Wqkv = (unsigned short*)(ws + 86580224);   //  6,291,456 B
    unsigned short* xb   = (unsigned short*)(ws + 92871680);   // 16,777,216 B
    unsigned short* vhat = (unsigned short*)(ws + 109648896);  // 16,777,216 B (end ~126.4 MB)

    convert_x<<<2048, 256, 0, stream>>>(x, xb, NTOK * D_DIM / 4);
    convert_w<<<dim3(1024, 4), 256, 0, stream>>>(Wq, Wk, Wv, Wo, Wqkv, Wob);
    twiddle_init<<<3, 256, 0, stream>>>(twg);

    dim3 gq(NTOK / BM, 3072 / BN);
    gemm_bf16_nt<unsigned short><<<gq, 256, 0, stream>>>(xb, Wqkv, QKVb, NTOK, 3072, D_DIM);

    hrr_fft_fwd<<<NTOK / 2, 256, 0, stream>>>(QKVb, twg, Fkv, Fq);

    dim3 gs((NF + 255) / 256, NCH, NB);
    hrr_chunk_sum<<<gs, 256, 0, stream>>>(Fkv, part);
    hrr_scan_apply<<<gs, 256, 0, stream>>>(Fkv, Fq, part);

    hrr_ifft<<<NTOK / 2, 256, 0, stream>>>(Fkv, twg, vhat);

    dim3 go(NTOK / BM, D_DIM / BN);
    gemm_bf16_nt<float><<<go, 256, 0, stream>>>(vhat, Wob, out, NTOK, D_DIM, D_DIM);
}

// Round 7
// 174.079 us; speedup vs baseline: 7.5062x; 1.0087x over previous
//
#include <hip/hip_runtime.h>

#define D_DIM 1024
#define NF 513            // rfft bins = D/2+1
#define NB 4              // batch
#define NS 2048           // sequence
#define NTOK (NB * NS)    // 8192 tokens
#define NCH 32            // cumsum chunks
#define CHS (NS / NCH)    // 64 steps per chunk

typedef __attribute__((ext_vector_type(8))) short short8_t;   // 8 bf16 = 4 VGPRs
typedef __attribute__((ext_vector_type(4))) float f32x4;

__device__ inline unsigned short f2bf(float f) {
    unsigned u = __builtin_bit_cast(unsigned, f);
    u += 0x7FFFu + ((u >> 16) & 1u);   // round-to-nearest-even
    return (unsigned short)(u >> 16);
}
__device__ inline float bf2f(unsigned short h) {
    unsigned u = ((unsigned)h) << 16;
    return __builtin_bit_cast(float, u);
}
__device__ inline unsigned pkc(float re, float im) {   // packed bf16 complex
    return (unsigned)f2bf(re) | ((unsigned)f2bf(im) << 16);
}
__device__ inline float2 upc(unsigned u) {
    return make_float2(bf2f((unsigned short)(u & 0xFFFFu)), bf2f((unsigned short)(u >> 16)));
}

__global__ __launch_bounds__(256) void convert_x(const float* __restrict__ src,
                                                 unsigned short* __restrict__ dst,
                                                 int n4) {
    int i = blockIdx.x * 256 + threadIdx.x;
    int stride = gridDim.x * 256;
    for (; i < n4; i += stride) {
        float4 v = reinterpret_cast<const float4*>(src)[i];
        ushort4 o;
        o.x = f2bf(v.x); o.y = f2bf(v.y); o.z = f2bf(v.z); o.w = f2bf(v.w);
        reinterpret_cast<ushort4*>(dst)[i] = o;
    }
}

// all four weights in one dispatch: gridDim.y selects the weight
__global__ __launch_bounds__(256) void convert_w(const float* __restrict__ Wq,
                                                 const float* __restrict__ Wk,
                                                 const float* __restrict__ Wv,
                                                 const float* __restrict__ Wo,
                                                 unsigned short* __restrict__ Wqkv,
                                                 unsigned short* __restrict__ Wob) {
    int y = blockIdx.y;
    const float* src = (y == 0) ? Wq : (y == 1) ? Wk : (y == 2) ? Wv : Wo;
    unsigned short* dst = (y < 3) ? (Wqkv + (size_t)y * 1048576) : Wob;
    int i = blockIdx.x * 256 + threadIdx.x;
    float4 v = reinterpret_cast<const float4*>(src)[i];
    ushort4 o;
    o.x = f2bf(v.x); o.y = f2bf(v.y); o.z = f2bf(v.z); o.w = f2bf(v.w);
    reinterpret_cast<ushort4*>(dst)[i] = o;
}

// ---------------------------------------------------------------------------
// bf16 MFMA GEMM: C[M,N] = A[M,K] * B[N,K]^T.  128x128 tile, BK=32.
// 3-buffer LDS pipeline, 2-tile stage lead, counted vmcnt (never 0 in steady
// state).  16B-slot XOR swizzle f(row)=(row>>1)&3 applied to BOTH the global
// staging source and the ds_read address (LDS dest stays linear, as required
// by global_load_lds): makes every ds_read_b128 exactly bank-balanced.
// ---------------------------------------------------------------------------
#define BM 128
#define BN 128
#define BK 32

__device__ inline void gload_lds16(const void* g, void* l) {
    __builtin_amdgcn_global_load_lds(
        (const __attribute__((address_space(1))) void*)g,
        (__attribute__((address_space(3))) void*)l,
        16, 0, 0);
}

template <typename OutT>
__global__ __launch_bounds__(256) void gemm_bf16_nt(const unsigned short* __restrict__ A,
                                                    const unsigned short* __restrict__ B,
                                                    OutT* __restrict__ C,
                                                    int M, int N, int K) {
    // 3 rotating buffers: [buf][BM*BK] for A, same for B.  48 KiB total.
    __shared__ __attribute__((aligned(16))) unsigned short ldsA[3 * BM * BK];
    __shared__ __attribute__((aligned(16))) unsigned short ldsB[3 * BM * BK];
    const int tid  = threadIdx.x;
    const int wave = tid >> 6;
    const int lane = tid & 63;
    const int l15  = lane & 15;
    // read-side swizzled slot: slot' = (lane>>4) ^ f(row), f(row)=(row>>1)&3.
    // row = (16-aligned base) + l15, so f(row) = (l15>>1)&3 -> per-thread const.
    const int k8   = (((lane >> 4) ^ ((l15 >> 1) & 3)) << 3);
    const int wm   = (wave >> 1) * 64;
    const int wn   = (wave & 1) * 64;
    const int bm   = blockIdx.x * BM;
    const int bn   = blockIdx.y * BN;
    const int crow = tid >> 2;               // staging row: 0..63 (c adds 64; f same)
    // write-side inverse swizzle on the GLOBAL source slot (dest stays linear):
    const int ccol = (((tid & 3) ^ ((tid >> 3) & 3)) << 3);
    const int NT   = K / BK;

    const unsigned short* Arow = A + (size_t)(bm + crow) * K + ccol;
    const unsigned short* Brow = B + (size_t)(bn + crow) * K + ccol;
    const size_t rstep = (size_t)64 * K;     // c=1 row offset

    f32x4 acc[4][4];
#pragma unroll
    for (int i = 0; i < 4; ++i)
#pragma unroll
        for (int j = 0; j < 4; ++j)
            acc[i][j] = (f32x4){0.f, 0.f, 0.f, 0.f};

    // STAGE(tile t -> buffer b): 4 global_load_lds instructions per wave.
    auto STAGE = [&](int t, int b) {
        const int k0 = t * BK;
        unsigned short* la = &ldsA[b * (BM * BK) + (tid >> 2) * BK + ((tid & 3) << 3)];
        unsigned short* lb = &ldsB[b * (BM * BK) + (tid >> 2) * BK + ((tid & 3) << 3)];
        gload_lds16(Arow + k0, la);
        gload_lds16(Brow + k0, lb);
        gload_lds16(Arow + rstep + k0, la + 64 * BK);
        gload_lds16(Brow + rstep + k0, lb + 64 * BK);
    };

    STAGE(0, 0);
    STAGE(1, 1);

    for (int j = 0; j < NT; ++j) {
        const int buf = j % 3;
        if (j + 2 < NT) STAGE(j + 2, (j + 2) % 3);

        // counted wait: tile j's loads landed; up to 2 tiles (8 insts) in flight.
        if (j + 2 < NT)      asm volatile("s_waitcnt vmcnt(8)" ::: "memory");
        else if (j + 1 < NT) asm volatile("s_waitcnt vmcnt(4)" ::: "memory");
        else                 asm volatile("s_waitcnt vmcnt(0)" ::: "memory");
        __builtin_amdgcn_s_barrier();           // all waves' tile-j loads visible
        asm volatile("" ::: "memory");          // pin LDS reads below barrier

        const unsigned short* la = &ldsA[buf * (BM * BK)];
        const unsigned short* lb = &ldsB[buf * (BM * BK)];
        short8_t af[4], bfv[4];
#pragma unroll
        for (int mi = 0; mi < 4; ++mi)
            af[mi] = *reinterpret_cast<const short8_t*>(&la[(wm + mi * 16 + l15) * BK + k8]);
#pragma unroll
        for (int ni = 0; ni < 4; ++ni)
            bfv[ni] = *reinterpret_cast<const short8_t*>(&lb[(wn + ni * 16 + l15) * BK + k8]);

        __builtin_amdgcn_s_setprio(1);
#pragma unroll
        for (int mi = 0; mi < 4; ++mi)
#pragma unroll
            for (int ni = 0; ni < 4; ++ni)
                acc[mi][ni] = __builtin_amdgcn_mfma_f32_16x16x32_bf16(af[mi], bfv[ni], acc[mi][ni], 0, 0, 0);
        __builtin_amdgcn_s_setprio(0);

        __builtin_amdgcn_s_barrier();           // reads done before buf reuse
        asm volatile("" ::: "memory");          // pin next STAGE below barrier
    }

#pragma unroll
    for (int mi = 0; mi < 4; ++mi) {
        int rbase = bm + wm + mi * 16 + (lane >> 4) * 4;
#pragma unroll
        for (int ni = 0; ni < 4; ++ni) {
            int col = bn + wn + ni * 16 + l15;
#pragma unroll
            for (int j = 0; j < 4; ++j) {
                float v = acc[mi][ni][j];
                if constexpr (sizeof(OutT) == 4)
                    C[(size_t)(rbase + j) * N + col] = v;
                else
                    C[(size_t)(rbase + j) * N + col] = f2bf(v);
            }
        }
    }
}

// ---------------------------------------------------------------------------
// Radix-4 1024-pt complex FFT in LDS, float2 elements, XOR bank swizzle.
// ---------------------------------------------------------------------------
__device__ inline int sw(int i) { return i ^ ((i >> 4) & 15); }

__device__ inline int dr4(int n) {   // reverse 5 base-4 digits of 10-bit n
    return ((n & 3) << 8) | (((n >> 2) & 3) << 6) | (((n >> 4) & 3) << 4) |
           (((n >> 6) & 3) << 2) | ((n >> 8) & 3);
}

__device__ inline float2 cmul(float2 a, float2 b) {
    return make_float2(a.x * b.x - a.y * b.y, a.x * b.y + a.y * b.x);
}

__device__ inline void fft1024_r4(float2* X, const float2* tw, int t) {
#pragma unroll
    for (int s = 0; s < 5; ++s) {
        const int L = 1 << (2 * s);
        const int r = t & (L - 1);
        const int base = ((t >> (2 * s)) << (2 * s + 2)) + r;
        float2 A  = X[sw(base)];
        float2 Bv = X[sw(base + L)];
        float2 Cv = X[sw(base + 2 * L)];
        float2 Dv = X[sw(base + 3 * L)];
        if (s != 0) {
            const int step = 1024 >> (2 * s + 2);
            Bv = cmul(Bv, tw[sw(r * step)]);
            Cv = cmul(Cv, tw[sw(2 * r * step)]);
            Dv = cmul(Dv, tw[sw(3 * r * step)]);
        }
        float2 e0 = make_float2(A.x + Cv.x, A.y + Cv.y);
        float2 e1 = make_float2(A.x - Cv.x, A.y - Cv.y);
        float2 o0 = make_float2(Bv.x + Dv.x, Bv.y + Dv.y);
        float2 o1 = make_float2(Bv.x - Dv.x, Bv.y - Dv.y);
        X[sw(base)]         = make_float2(e0.x + o0.x, e0.y + o0.y);
        X[sw(base + L)]     = make_float2(e1.x + o1.y, e1.y - o1.x);
        X[sw(base + 2 * L)] = make_float2(e0.x - o0.x, e0.y - o0.y);
        X[sw(base + 3 * L)] = make_float2(e1.x - o1.y, e1.y + o1.x);
        __syncthreads();
    }
}

__global__ __launch_bounds__(256) void twiddle_init(float2* __restrict__ twg) {
    int k = blockIdx.x * 256 + threadIdx.x;
    if (k < 768) {
        float ang = -6.283185307179586f * (float)k / 1024.0f;
        float s, c;
        sincosf(ang, &s, &c);
        twg[sw(k)] = make_float2(c, s);
    }
}

// ---------------------------------------------------------------------------
// Forward: block handles tokens (2b, 2b+1). QKV is bf16 [tok][3072] = q|k|v.
// Outputs packed-bf16 complex Fkv, Fq.
// ---------------------------------------------------------------------------
__global__ __launch_bounds__(256) void hrr_fft_fwd(const unsigned short* __restrict__ QKV,
                                                   const float2* __restrict__ twg,
                                                   unsigned* __restrict__ Fkv,
                                                   unsigned* __restrict__ Fq) {
    __shared__ __attribute__((aligned(16))) float2 X[1024];
    __shared__ __attribute__((aligned(16))) float2 twL[768];
    const int tid = threadIdx.x;
    const int t0 = blockIdx.x * 2, t1 = t0 + 1;
    for (int i = tid; i < 384; i += 256)
        reinterpret_cast<float4*>(twL)[i] = reinterpret_cast<const float4*>(twg)[i];

#pragma unroll
    for (int which = 0; which < 2; ++which) {
        const int tok = which ? t1 : t0;
        const ushort4* Kr = (const ushort4*)(QKV + (size_t)tok * 3072 + 1024);
        const ushort4* Vr = (const ushort4*)(QKV + (size_t)tok * 3072 + 2048);
        ushort4 k4 = Kr[tid], v4 = Vr[tid];
        X[sw(dr4(4 * tid + 0))] = make_float2(bf2f(k4.x), bf2f(v4.x));
        X[sw(dr4(4 * tid + 1))] = make_float2(bf2f(k4.y), bf2f(v4.y));
        X[sw(dr4(4 * tid + 2))] = make_float2(bf2f(k4.z), bf2f(v4.z));
        X[sw(dr4(4 * tid + 3))] = make_float2(bf2f(k4.w), bf2f(v4.w));
        __syncthreads();
        fft1024_r4(X, twL, tid);
        for (int j = tid; j < NF; j += 256) {
            float2 Zj = X[sw(j)];
            float2 Zm = X[sw((1024 - j) & 1023)];
            float2 Fk = make_float2(0.5f * (Zj.x + Zm.x), 0.5f * (Zj.y - Zm.y));
            float2 Fv = make_float2(0.5f * (Zj.y + Zm.y), 0.5f * (Zm.x - Zj.x));
            float2 p = cmul(Fk, Fv);
            Fkv[(size_t)tok * NF + j] = pkc(p.x, p.y);
        }
        __syncthreads();
    }
    // Q pair
    {
        const ushort4* Q0 = (const ushort4*)(QKV + (size_t)t0 * 3072);
        const ushort4* Q1 = (const ushort4*)(QKV + (size_t)t1 * 3072);
        ushort4 a4 = Q0[tid], b4 = Q1[tid];
        X[sw(dr4(4 * tid + 0))] = make_float2(bf2f(a4.x), bf2f(b4.x));
        X[sw(dr4(4 * tid + 1))] = make_float2(bf2f(a4.y), bf2f(b4.y));
        X[sw(dr4(4 * tid + 2))] = make_float2(bf2f(a4.z), bf2f(b4.z));
        X[sw(dr4(4 * tid + 3))] = make_float2(bf2f(a4.w), bf2f(b4.w));
        __syncthreads();
        fft1024_r4(X, twL, tid);
        for (int j = tid; j < NF; j += 256) {
            float2 Zj = X[sw(j)];
            float2 Zm = X[sw((1024 - j) & 1023)];
            Fq[(size_t)t0 * NF + j] = pkc(0.5f * (Zj.x + Zm.x), 0.5f * (Zj.y - Zm.y));
            Fq[(size_t)t1 * NF + j] = pkc(0.5f * (Zj.y + Zm.y), 0.5f * (Zm.x - Zj.x));
        }
    }
}

// ---------------------------------------------------------------------------
// Chunked causal cumsum (fp32 accumulation over bf16 terms).
// ---------------------------------------------------------------------------
__global__ __launch_bounds__(256) void hrr_chunk_sum(const unsigned* __restrict__ Fkv,
                                                     float2* __restrict__ part) {
    int f = blockIdx.x * 256 + threadIdx.x;
    if (f >= NF) return;
    int ch = blockIdx.y, b = blockIdx.z;
    float sx = 0.f, sy = 0.f;
    size_t base = ((size_t)b * NS + (size_t)ch * CHS) * NF + f;
    for (int i = 0; i < CHS; ++i) {
        float2 t = upc(Fkv[base + (size_t)i * NF]);
        sx += t.x; sy += t.y;
    }
    part[(size_t)(b * NCH + ch) * NF + f] = make_float2(sx, sy);
}

// exclusive prefix of chunk totals computed inline (part is small + L2-hot),
// then running cumsum * conj(Fq) -> U, written in place over Fkv (bf16).
__global__ __launch_bounds__(256) void hrr_scan_apply(unsigned* __restrict__ Fkv,
                                                      const unsigned* __restrict__ Fq,
                                                      const float2* __restrict__ part) {
    int f = blockIdx.x * 256 + threadIdx.x;
    if (f >= NF) return;
    int ch = blockIdx.y, b = blockIdx.z;
    float rx = 0.f, ry = 0.f;
    for (int c2 = 0; c2 < ch; ++c2) {
        float2 p = part[(size_t)(b * NCH + c2) * NF + f];
        rx += p.x; ry += p.y;
    }
    size_t base = ((size_t)b * NS + (size_t)ch * CHS) * NF + f;
    for (int i = 0; i < CHS; ++i) {
        size_t idx = base + (size_t)i * NF;
        float2 kv = upc(Fkv[idx]);
        rx += kv.x; ry += kv.y;
        float2 q = upc(Fq[idx]);
        Fkv[idx] = pkc(rx * q.x + ry * q.y, ry * q.x - rx * q.y);
    }
}

// ---------------------------------------------------------------------------
// Paired irfft of bf16 U; writes vhat bf16.
// ---------------------------------------------------------------------------
__global__ __launch_bounds__(256) void hrr_ifft(const unsigned* __restrict__ U,
                                                const float2* __restrict__ twg,
                                                unsigned short* __restrict__ vhat) {
    __shared__ __attribute__((aligned(16))) float2 X[1024];
    __shared__ __attribute__((aligned(16))) float2 twL[768];
    const int tid = threadIdx.x;
    const int t0 = blockIdx.x * 2, t1 = t0 + 1;
    for (int i = tid; i < 384; i += 256)
        reinterpret_cast<float4*>(twL)[i] = reinterpret_cast<const float4*>(twg)[i];
    const unsigned* U1 = U + (size_t)t0 * NF;
    const unsigned* U2 = U + (size_t)t1 * NF;
#pragma unroll
    for (int c = 0; c < 4; ++c) {
        int j = tid + (c << 8);
        float2 Cv;
        if (j <= 512) {
            float2 u1 = upc(U1[j]), u2 = upc(U2[j]);
            Cv = make_float2(u1.x - u2.y, -u1.y - u2.x);
        } else {
            int m = 1024 - j;
            float2 u1 = upc(U1[m]), u2 = upc(U2[m]);
            Cv = make_float2(u1.x + u2.y, u1.y - u2.x);
        }
        X[sw(dr4(j))] = Cv;
    }
    __syncthreads();
    fft1024_r4(X, twL, tid);
    const float invN = 1.0f / 1024.0f;
#pragma unroll
    for (int c = 0; c < 4; ++c) {
        int n = tid + (c << 8);
        float2 w = X[sw(n)];
        vhat[(size_t)t0 * D_DIM + n] = f2bf(w.x * invN);
        vhat[(size_t)t1 * D_DIM + n] = f2bf(-w.y * invN);
    }
}

// ---------------------------------------------------------------------------
extern "C" void kernel_launch(void* const* d_in, const int* in_sizes, int n_in,
                              void* d_out, int out_size, void* d_ws, size_t ws_size,
                              hipStream_t stream) {
    const float* x  = (const float*)d_in[0];
    const float* Wq = (const float*)d_in[1];
    const float* Wk = (const float*)d_in[2];
    const float* Wv = (const float*)d_in[3];
    const float* Wo = (const float*)d_in[4];
    float* out = (float*)d_out;

    char* ws = (char*)d_ws;
    unsigned short* QKVb = (unsigned short*)(ws + 0);          // 50,331,648 B
    unsigned*       Fkv  = (unsigned*)      (ws + 50331648);   // 16,809,984 B
    unsigned*       Fq   = (unsigned*)      (ws + 67141632);   // 16,809,984 B
    float2*         part = (float2*)        (ws + 83951616);   //    525,312 B
    float2*         twg  = (float2*)        (ws + 84476928);   //      6,144 B
    unsigned short* Wob  = (unsigned short*)(ws + 84483072);   //  2,097,152 B
    unsigned short* Wqkv = (unsigned short*)(ws + 86580224);   //  6,291,456 B
    unsigned short* xb   = (unsigned short*)(ws + 92871680);   // 16,777,216 B
    unsigned short* vhat = (unsigned short*)(ws + 109648896);  // 16,777,216 B (end ~126.4 MB)

    convert_x<<<2048, 256, 0, stream>>>(x, xb, NTOK * D_DIM / 4);
    convert_w<<<dim3(1024, 4), 256, 0, stream>>>(Wq, Wk, Wv, Wo, Wqkv, Wob);
    twiddle_init<<<3, 256, 0, stream>>>(twg);

    dim3 gq(NTOK / BM, 3072 / BN);
    gemm_bf16_nt<unsigned short><<<gq, 256, 0, stream>>>(xb, Wqkv, QKVb, NTOK, 3072, D_DIM);

    hrr_fft_fwd<<<NTOK / 2, 256, 0, stream>>>(QKVb, twg, Fkv, Fq);

    dim3 gs((NF + 255) / 256, NCH, NB);
    hrr_chunk_sum<<<gs, 256, 0, stream>>>(Fkv, part);
    hrr_scan_apply<<<gs, 256, 0, stream>>>(Fkv, Fq, part);

    hrr_ifft<<<NTOK / 2, 256, 0, stream>>>(Fkv, twg, vhat);

    dim3 go(NTOK / BM, D_DIM / BN);
    gemm_bf16_nt<float><<<go, 256, 0, stream>>>(vhat, Wob, out, NTOK, D_DIM, D_DIM);
}